// Round 1
// baseline (535.569 us; speedup 1.0000x reference)
//
#include <hip/hip_runtime.h>

constexpr int TPB = 256;

// ---------------- init: deg = 1.0 (self loop), flag = 0 ----------------
__global__ void k_init(float* deg, int N, int* flag) {
    int i = blockIdx.x * TPB + threadIdx.x;
    if (i < N) deg[i] = 1.0f;
    if (blockIdx.x == 0 && threadIdx.x == 0) *flag = 0;
}

// ---------------- detect edge_index dtype (int64 vs int32) ----------------
// int64 little-endian: odd int32 words are high words == 0 (ids < 2^31).
// int32: odd words are node ids, overwhelmingly nonzero. Only reads within
// the first 2E int32 words (safe under both interpretations).
__global__ void k_detect(const int* ei32, int E, int* flag) {
    int t = blockIdx.x * TPB + threadIdx.x;
    int v = 0;
    if (t < E) v = ei32[2 * t + 1];
    unsigned long long b = __ballot(v != 0);
    if ((threadIdx.x & 63) == 0 && b != 0ULL) atomicOr(flag, 1);
}

__device__ __forceinline__ void load_rc(const void* ei, int e, int E, int is32,
                                        int& r, int& c) {
    if (is32) {
        const int* p = (const int*)ei;
        r = p[e]; c = p[E + e];
    } else {
        const long long* p = (const long long*)ei;
        r = (int)p[e]; c = (int)p[E + e];
    }
}

// ---------------- degree accumulation ----------------
__global__ void k_degree(const void* ei, const float* __restrict__ ew,
                         float* deg, int E, const int* flag) {
    int e = blockIdx.x * TPB + threadIdx.x;
    if (e >= E) return;
    int is32 = *flag;
    int r, c; load_rc(ei, e, E, is32, r, c);
    float hw = 0.5f * ew[e];
    unsafeAtomicAdd(&deg[r], hw);
    unsafeAtomicAdd(&deg[c], hw);
}

__global__ void k_rsqrt(float* degdis, int N) {
    int i = blockIdx.x * TPB + threadIdx.x;
    if (i < N) {
        float d = degdis[i];
        degdis[i] = d > 0.f ? rsqrtf(d) : 0.f;
    }
}

// ---------------- Y[N,64] = X[N,64] @ W[64,64], W staged in LDS ----------------
__global__ void k_gemm_nk64(const float* __restrict__ X, const float* __restrict__ W,
                            float* __restrict__ Y, int N) {
    __shared__ float Wl[64 * 64];
    int tid = threadIdx.x;
    #pragma unroll
    for (int i = tid; i < 4096; i += TPB) Wl[i] = W[i];
    __syncthreads();
    int row = blockIdx.x * 4 + (tid >> 6);
    int f = tid & 63;
    if (row >= N) return;
    const float* xr = X + row * 64;
    float s = 0.f;
    #pragma unroll
    for (int k = 0; k < 64; ++k) s = fmaf(xr[k], Wl[k * 64 + f], s);
    Y[row * 64 + f] = s;
}

// ---------------- Z = dis .* Y ; ACC = Z (self-loop init) ----------------
__global__ void k_scale_init(const float* __restrict__ Y, const float* __restrict__ dis,
                             float* __restrict__ Z, float* __restrict__ ACC, int total) {
    int i = blockIdx.x * TPB + threadIdx.x;
    if (i < total) {
        float z = dis[i >> 6] * Y[i];
        Z[i] = z;
        ACC[i] = z;
    }
}

// ---------------- edge scatter: ACC[r] += w/2 * Z[c]; ACC[c] += w/2 * Z[r] ----------------
template <int LOGD>
__global__ void k_scatter(const void* ei, const float* __restrict__ ew,
                          const float* __restrict__ Z, float* ACC, int E,
                          const int* flag) {
    constexpr int D = 1 << LOGD;
    int gid = blockIdx.x * TPB + threadIdx.x;
    int e = gid >> LOGD;
    int f = gid & (D - 1);
    if (e >= E) return;
    int is32 = *flag;
    int r, c; load_rc(ei, e, E, is32, r, c);
    float hw = 0.5f * ew[e];
    float zc = Z[c * D + f];
    float zr = Z[r * D + f];
    unsafeAtomicAdd(&ACC[r * D + f], hw * zc);
    unsafeAtomicAdd(&ACC[c * D + f], hw * zr);
}

// ---------------- H = relu(dis .* ACC + b1) in place ----------------
__global__ void k_relu_bias(float* __restrict__ A1, const float* __restrict__ dis,
                            const float* __restrict__ b1, int total) {
    int i = blockIdx.x * TPB + threadIdx.x;
    if (i < total) {
        float v = dis[i >> 6] * A1[i] + b1[i & 63];
        A1[i] = v > 0.f ? v : 0.f;
    }
}

// ---------------- Y2 = H @ W2[64,16]; Z2 = dis.*Y2; ACC2 = Z2 ----------------
__global__ void k_gemm2_scale(const float* __restrict__ H, const float* __restrict__ W2,
                              const float* __restrict__ dis, float* __restrict__ Z2,
                              float* __restrict__ ACC2, int N) {
    __shared__ float Wl[64 * 16];
    int tid = threadIdx.x;
    #pragma unroll
    for (int i = tid; i < 1024; i += TPB) Wl[i] = W2[i];
    __syncthreads();
    int row = blockIdx.x * 16 + (tid >> 4);
    int f = tid & 15;
    if (row >= N) return;
    const float* hr = H + row * 64;
    float s = 0.f;
    #pragma unroll
    for (int k = 0; k < 64; ++k) s = fmaf(hr[k], Wl[k * 16 + f], s);
    float z = dis[row] * s;
    int o = row * 16 + f;
    Z2[o] = z;
    ACC2[o] = z;
}

// ---------------- out = dis .* ACC2 + b2 ----------------
__global__ void k_final(const float* __restrict__ A2, const float* __restrict__ dis,
                        const float* __restrict__ b2, float* __restrict__ out, int total) {
    int i = blockIdx.x * TPB + threadIdx.x;
    if (i < total) out[i] = dis[i >> 4] * A2[i] + b2[i & 15];
}

extern "C" void kernel_launch(void* const* d_in, const int* in_sizes, int n_in,
                              void* d_out, int out_size, void* d_ws, size_t ws_size,
                              hipStream_t stream) {
    const float* x  = (const float*)d_in[0];
    const float* W1 = (const float*)d_in[1];
    const float* b1 = (const float*)d_in[2];
    const float* W2 = (const float*)d_in[3];
    const float* b2 = (const float*)d_in[4];
    const float* ew = (const float*)d_in[5];
    const void*  ei = d_in[6];

    const int N = in_sizes[0] / 64;   // 16384
    const int E = in_sizes[5];        // 524288

    char* ws = (char*)d_ws;
    size_t off = 0;
    auto alloc = [&](size_t bytes) -> void* {
        void* p = ws + off;
        off += (bytes + 255) & ~(size_t)255;
        return p;
    };
    int*   flag = (int*)alloc(256);
    float* dis  = (float*)alloc((size_t)N * 4);           // deg -> dis in place
    float* Y1   = (float*)alloc((size_t)N * 64 * 4);
    float* Z1   = (float*)alloc((size_t)N * 64 * 4);
    float* A1   = (float*)alloc((size_t)N * 64 * 4);      // ACC1, then H in place
    float* Z2   = (float*)alloc((size_t)N * 16 * 4);
    float* A2   = (float*)alloc((size_t)N * 16 * 4);
    (void)ws_size; (void)n_in; (void)out_size;

    float* out = (float*)d_out;

    k_init<<<(N + TPB - 1) / TPB, TPB, 0, stream>>>(dis, N, flag);
    k_detect<<<(E + TPB - 1) / TPB, TPB, 0, stream>>>((const int*)ei, E, flag);
    k_degree<<<(E + TPB - 1) / TPB, TPB, 0, stream>>>(ei, ew, dis, E, flag);
    k_rsqrt<<<(N + TPB - 1) / TPB, TPB, 0, stream>>>(dis, N);

    k_gemm_nk64<<<(N + 3) / 4, TPB, 0, stream>>>(x, W1, Y1, N);
    k_scale_init<<<(N * 64 + TPB - 1) / TPB, TPB, 0, stream>>>(Y1, dis, Z1, A1, N * 64);
    k_scatter<6><<<(int)(((long long)E * 64 + TPB - 1) / TPB), TPB, 0, stream>>>(ei, ew, Z1, A1, E, flag);
    k_relu_bias<<<(N * 64 + TPB - 1) / TPB, TPB, 0, stream>>>(A1, dis, b1, N * 64);

    k_gemm2_scale<<<(N + 15) / 16, TPB, 0, stream>>>(A1, W2, dis, Z2, A2, N);
    k_scatter<4><<<(int)(((long long)E * 16 + TPB - 1) / TPB), TPB, 0, stream>>>(ei, ew, Z2, A2, E, flag);
    k_final<<<(N * 16 + TPB - 1) / TPB, TPB, 0, stream>>>(A2, dis, b2, out, N * 16);
}

// Round 2
// 477.389 us; speedup vs baseline: 1.1219x; 1.1219x over previous
//
#include <hip/hip_runtime.h>

constexpr int TPB = 256;

// ---------------- init: deg = 1.0 (self loop), counts = 0, flag = 0 ----------------
__global__ void k_init(float* deg, int* counts, int N, int* flag) {
    int i = blockIdx.x * TPB + threadIdx.x;
    if (i < N) { deg[i] = 1.0f; counts[i] = 0; }
    if (blockIdx.x == 0 && threadIdx.x == 0) *flag = 0;
}

// ---------------- detect edge_index dtype (int64 vs int32) ----------------
__global__ void k_detect(const int* ei32, int E, int* flag) {
    int t = blockIdx.x * TPB + threadIdx.x;
    int v = 0;
    if (t < E) v = ei32[2 * t + 1];
    unsigned long long b = __ballot(v != 0);
    if ((threadIdx.x & 63) == 0 && b != 0ULL) atomicOr(flag, 1);
}

__device__ __forceinline__ void load_rc(const void* ei, int e, int E, int is32,
                                        int& r, int& c) {
    if (is32) {
        const int* p = (const int*)ei;
        r = p[e]; c = p[E + e];
    } else {
        const long long* p = (const long long*)ei;
        r = (int)p[e]; c = (int)p[E + e];
    }
}

// ---------------- degree accumulation + CSR row counts ----------------
__global__ void k_deg_cnt(const void* ei, const float* __restrict__ ew,
                          float* deg, int* counts, int E, const int* flag) {
    int e = blockIdx.x * TPB + threadIdx.x;
    if (e >= E) return;
    int is32 = *flag;
    int r, c; load_rc(ei, e, E, is32, r, c);
    float hw = 0.5f * ew[e];
    unsafeAtomicAdd(&deg[r], hw);
    unsafeAtomicAdd(&deg[c], hw);
    atomicAdd(&counts[r], 1);
    atomicAdd(&counts[c], 1);
}

__global__ void k_rsqrt(float* degdis, int N) {
    int i = blockIdx.x * TPB + threadIdx.x;
    if (i < N) {
        float d = degdis[i];
        degdis[i] = d > 0.f ? rsqrtf(d) : 0.f;
    }
}

// ---------------- single-block exclusive scan over counts -> rowptr, cursor ----------------
__global__ void k_scan(const int* __restrict__ counts, int* __restrict__ rowptr,
                       int* __restrict__ cursor, int N) {
    __shared__ int partial[TPB];
    int tid = threadIdx.x;
    int chunk = (N + TPB - 1) / TPB;
    int begin = tid * chunk;
    int end = begin + chunk; if (end > N) end = N;
    int s = 0;
    for (int i = begin; i < end; ++i) s += counts[i];
    partial[tid] = s;
    __syncthreads();
    for (int off = 1; off < TPB; off <<= 1) {
        int v = partial[tid];
        int add = (tid >= off) ? partial[tid - off] : 0;
        __syncthreads();
        partial[tid] = v + add;
        __syncthreads();
    }
    int base = (tid == 0) ? 0 : partial[tid - 1];
    for (int i = begin; i < end; ++i) {
        rowptr[i] = base; cursor[i] = base;
        base += counts[i];
    }
    if (tid == TPB - 1) rowptr[N] = base;
}

// ---------------- fill CSR: for edge (r,c,w): row r gets (c,w/2), row c gets (r,w/2) ----------------
__global__ void k_fill(const void* ei, const float* __restrict__ ew, int* cursor,
                       int* __restrict__ nbr, float* __restrict__ wgt,
                       int E, const int* flag) {
    int e = blockIdx.x * TPB + threadIdx.x;
    if (e >= E) return;
    int is32 = *flag;
    int r, c; load_rc(ei, e, E, is32, r, c);
    float hw = 0.5f * ew[e];
    int p1 = atomicAdd(&cursor[r], 1);
    nbr[p1] = c; wgt[p1] = hw;
    int p2 = atomicAdd(&cursor[c], 1);
    nbr[p2] = r; wgt[p2] = hw;
}

// ---------------- Z1[N,64] = dis .* (X[N,64] @ W1[64,64]) ----------------
__global__ void k_gemm1(const float* __restrict__ X, const float* __restrict__ W,
                        const float* __restrict__ dis, float* __restrict__ Z, int N) {
    __shared__ float Wl[64 * 64];
    int tid = threadIdx.x;
    #pragma unroll
    for (int i = tid; i < 4096; i += TPB) Wl[i] = W[i];
    __syncthreads();
    int row = blockIdx.x * 4 + (tid >> 6);
    int f = tid & 63;
    if (row >= N) return;
    const float* xr = X + row * 64;
    float s = 0.f;
    #pragma unroll
    for (int k = 0; k < 64; ++k) s = fmaf(xr[k], Wl[k * 64 + f], s);
    Z[row * 64 + f] = dis[row] * s;
}

// ---------------- gather: out[n,f] = epi( dis[n]*(Z[n,f] + sum_j w_j Z[nbr_j,f]) + bias[f] ) ----------------
template <int D, bool RELU>
__global__ void k_gather(const float* __restrict__ Z, const int* __restrict__ rowptr,
                         const int* __restrict__ nbr, const float* __restrict__ wgt,
                         const float* __restrict__ dis, const float* __restrict__ bias,
                         float* __restrict__ out, int N) {
    constexpr int NPB = TPB / D;
    int node = blockIdx.x * NPB + threadIdx.x / D;
    int f = threadIdx.x % D;
    if (node >= N) return;
    int j = rowptr[node];
    int jend = rowptr[node + 1];
    float acc = Z[node * D + f];
    int nn = 0; float ww = 0.f;
    if (j < jend) { nn = nbr[j]; ww = wgt[j]; }
    while (j < jend) {
        int cn = nn; float cw = ww;
        ++j;
        if (j < jend) { nn = nbr[j]; ww = wgt[j]; }  // prefetch next index/weight
        acc = fmaf(cw, Z[cn * D + f], acc);
    }
    float v = fmaf(dis[node], acc, bias[f]);
    if (RELU) v = v > 0.f ? v : 0.f;
    out[node * D + f] = v;
}

// ---------------- Z2[N,16] = dis .* (H[N,64] @ W2[64,16]) ----------------
__global__ void k_gemm2(const float* __restrict__ H, const float* __restrict__ W2,
                        const float* __restrict__ dis, float* __restrict__ Z2, int N) {
    __shared__ float Wl[64 * 16];
    int tid = threadIdx.x;
    #pragma unroll
    for (int i = tid; i < 1024; i += TPB) Wl[i] = W2[i];
    __syncthreads();
    int row = blockIdx.x * 16 + (tid >> 4);
    int f = tid & 15;
    if (row >= N) return;
    const float* hr = H + row * 64;
    float s = 0.f;
    #pragma unroll
    for (int k = 0; k < 64; ++k) s = fmaf(hr[k], Wl[k * 16 + f], s);
    Z2[row * 16 + f] = dis[row] * s;
}

extern "C" void kernel_launch(void* const* d_in, const int* in_sizes, int n_in,
                              void* d_out, int out_size, void* d_ws, size_t ws_size,
                              hipStream_t stream) {
    const float* x  = (const float*)d_in[0];
    const float* W1 = (const float*)d_in[1];
    const float* b1 = (const float*)d_in[2];
    const float* W2 = (const float*)d_in[3];
    const float* b2 = (const float*)d_in[4];
    const float* ew = (const float*)d_in[5];
    const void*  ei = d_in[6];

    const int N = in_sizes[0] / 64;   // 16384
    const int E = in_sizes[5];        // 524288
    const int M = 2 * E;              // CSR entries

    char* ws = (char*)d_ws;
    size_t off = 0;
    auto alloc = [&](size_t bytes) -> void* {
        void* p = ws + off;
        off += (bytes + 255) & ~(size_t)255;
        return p;
    };
    int*   flag   = (int*)alloc(256);
    float* dis    = (float*)alloc((size_t)N * 4);
    int*   counts = (int*)alloc((size_t)N * 4);
    int*   rowptr = (int*)alloc(((size_t)N + 1) * 4);
    int*   cursor = (int*)alloc((size_t)N * 4);
    int*   nbr    = (int*)alloc((size_t)M * 4);
    float* wgt    = (float*)alloc((size_t)M * 4);
    float* Z1     = (float*)alloc((size_t)N * 64 * 4);
    float* H      = (float*)alloc((size_t)N * 64 * 4);
    float* Z2     = (float*)alloc((size_t)N * 16 * 4);
    (void)ws_size; (void)n_in; (void)out_size;

    float* out = (float*)d_out;

    // graph prep
    k_init<<<(N + TPB - 1) / TPB, TPB, 0, stream>>>(dis, counts, N, flag);
    k_detect<<<(E + TPB - 1) / TPB, TPB, 0, stream>>>((const int*)ei, E, flag);
    k_deg_cnt<<<(E + TPB - 1) / TPB, TPB, 0, stream>>>(ei, ew, dis, counts, E, flag);
    k_rsqrt<<<(N + TPB - 1) / TPB, TPB, 0, stream>>>(dis, N);
    k_scan<<<1, TPB, 0, stream>>>(counts, rowptr, cursor, N);
    k_fill<<<(E + TPB - 1) / TPB, TPB, 0, stream>>>(ei, ew, cursor, nbr, wgt, E, flag);

    // layer 1
    k_gemm1<<<(N + 3) / 4, TPB, 0, stream>>>(x, W1, dis, Z1, N);
    k_gather<64, true><<<(N + 3) / 4, TPB, 0, stream>>>(Z1, rowptr, nbr, wgt, dis, b1, H, N);

    // layer 2
    k_gemm2<<<(N + 15) / 16, TPB, 0, stream>>>(H, W2, dis, Z2, N);
    k_gather<16, false><<<(N + 15) / 16, TPB, 0, stream>>>(Z2, rowptr, nbr, wgt, dis, b2, out, N);
}

// Round 3
// 364.072 us; speedup vs baseline: 1.4711x; 1.3112x over previous
//
#include <hip/hip_runtime.h>

constexpr int TPB = 256;
constexpr int HB  = 64;      // histogram blocks
constexpr int NMAX = 16384;  // LDS histogram capacity (ints -> 64 KB)

// ---------------- flag = 0 ----------------
__global__ void k_flag0(int* flag) { if (threadIdx.x == 0) *flag = 0; }

// ---------------- detect edge_index dtype (int64 vs int32) ----------------
// int64 little-endian: odd int32 words are high words == 0 (ids < 2^31).
__global__ void k_detect(const int* ei32, int E, int* flag) {
    int t = blockIdx.x * TPB + threadIdx.x;
    int v = 0;
    if (t < E) v = ei32[2 * t + 1];
    unsigned long long b = __ballot(v != 0);
    if ((threadIdx.x & 63) == 0 && b != 0ULL) atomicOr(flag, 1);
}

__device__ __forceinline__ void load_rc(const void* ei, int e, int E, int is32,
                                        int& r, int& c) {
    if (is32) {
        const int* p = (const int*)ei;
        r = p[e]; c = p[E + e];
    } else {
        const long long* p = (const long long*)ei;
        r = (int)p[e]; c = (int)p[E + e];
    }
}

// ---------------- pass A: per-block LDS histogram of endpoint counts ----------------
__global__ void k_count(const void* ei, int E, const int* flag,
                        int* __restrict__ partial, int N) {
    __shared__ int cnt[NMAX];
    for (int i = threadIdx.x; i < N; i += TPB) cnt[i] = 0;
    __syncthreads();
    int is32 = *flag;
    int chunk = (E + HB - 1) / HB;
    int b = blockIdx.x;
    int e0 = b * chunk;
    int e1 = e0 + chunk; if (e1 > E) e1 = E;
    for (int e = e0 + threadIdx.x; e < e1; e += TPB) {
        int r, c; load_rc(ei, e, E, is32, r, c);
        atomicAdd(&cnt[r], 1);
        atomicAdd(&cnt[c], 1);
    }
    __syncthreads();
    for (int i = threadIdx.x; i < N; i += TPB) partial[b * N + i] = cnt[i];
}

// ---------------- pass B: per-node exclusive prefix over blocks (in place) ----------------
__global__ void k_reduce(int* __restrict__ partial, int* __restrict__ counts, int N) {
    int i = blockIdx.x * TPB + threadIdx.x;
    if (i >= N) return;
    int run = 0;
    for (int b = 0; b < HB; ++b) {
        int v = partial[b * N + i];
        partial[b * N + i] = run;
        run += v;
    }
    counts[i] = run;
}

// ---------------- pass C: exclusive scan counts -> rowptr (LDS-staged) ----------------
__global__ void k_scan2(const int* __restrict__ counts, int* __restrict__ rowptr, int N) {
    __shared__ int v[NMAX];
    __shared__ int part[TPB];
    int tid = threadIdx.x;
    for (int i = tid; i < N; i += TPB) v[i] = counts[i];
    __syncthreads();
    int chunk = (N + TPB - 1) / TPB;
    int b0 = tid * chunk;
    int b1 = b0 + chunk; if (b1 > N) b1 = N;
    int s = 0;
    for (int i = b0; i < b1; ++i) s += v[i];
    part[tid] = s;
    __syncthreads();
    for (int off = 1; off < TPB; off <<= 1) {
        int t = part[tid];
        int add = (tid >= off) ? part[tid - off] : 0;
        __syncthreads();
        part[tid] = t + add;
        __syncthreads();
    }
    int base = (tid == 0) ? 0 : part[tid - 1];
    for (int i = b0; i < b1; ++i) { int t = v[i]; v[i] = base; base += t; }
    __syncthreads();
    for (int i = tid; i < N; i += TPB) rowptr[i] = v[i];
    if (tid == TPB - 1) rowptr[N] = part[TPB - 1];
}

// ---------------- pass D: CSR fill with LDS cursors (no global atomics) ----------------
__global__ void k_fill2(const void* ei, const float* __restrict__ ew, const int* flag,
                        const int* __restrict__ rowptr, const int* __restrict__ partial,
                        int* __restrict__ nbr, float* __restrict__ wgt, int E, int N) {
    __shared__ int cur[NMAX];
    int b = blockIdx.x;
    for (int i = threadIdx.x; i < N; i += TPB) cur[i] = rowptr[i] + partial[b * N + i];
    __syncthreads();
    int is32 = *flag;
    int chunk = (E + HB - 1) / HB;
    int e0 = b * chunk;
    int e1 = e0 + chunk; if (e1 > E) e1 = E;
    for (int e = e0 + threadIdx.x; e < e1; e += TPB) {
        int r, c; load_rc(ei, e, E, is32, r, c);
        float hw = 0.5f * ew[e];
        int p1 = atomicAdd(&cur[r], 1);
        nbr[p1] = c; wgt[p1] = hw;
        int p2 = atomicAdd(&cur[c], 1);
        nbr[p2] = r; wgt[p2] = hw;
    }
}

// ---------------- pass E: dis[i] = rsqrt(1 + sum(wgt row i)), wave per node ----------------
__global__ void k_deg_dis(const int* __restrict__ rowptr, const float* __restrict__ wgt,
                          float* __restrict__ dis, int N) {
    int wv = (blockIdx.x * TPB + threadIdx.x) >> 6;
    int lane = threadIdx.x & 63;
    if (wv >= N) return;
    int j0 = rowptr[wv], j1 = rowptr[wv + 1];
    float s = 0.f;
    for (int j = j0 + lane; j < j1; j += 64) s += wgt[j];
    #pragma unroll
    for (int off = 32; off; off >>= 1) s += __shfl_down(s, off, 64);
    if (lane == 0) dis[wv] = rsqrtf(1.f + s);
}

// ============ fallback path (N > NMAX): global-atomic prep ============
__global__ void k_init_fb(float* deg, int* counts, int N) {
    int i = blockIdx.x * TPB + threadIdx.x;
    if (i < N) { deg[i] = 1.0f; counts[i] = 0; }
}
__global__ void k_deg_cnt_fb(const void* ei, const float* __restrict__ ew,
                             float* deg, int* counts, int E, const int* flag) {
    int e = blockIdx.x * TPB + threadIdx.x;
    if (e >= E) return;
    int is32 = *flag;
    int r, c; load_rc(ei, e, E, is32, r, c);
    float hw = 0.5f * ew[e];
    unsafeAtomicAdd(&deg[r], hw);
    unsafeAtomicAdd(&deg[c], hw);
    atomicAdd(&counts[r], 1);
    atomicAdd(&counts[c], 1);
}
__global__ void k_rsqrt_fb(float* degdis, int N) {
    int i = blockIdx.x * TPB + threadIdx.x;
    if (i < N) {
        float d = degdis[i];
        degdis[i] = d > 0.f ? rsqrtf(d) : 0.f;
    }
}
__global__ void k_scan_fb(const int* __restrict__ counts, int* __restrict__ rowptr,
                          int* __restrict__ cursor, int N) {
    __shared__ int partial[TPB];
    int tid = threadIdx.x;
    int chunk = (N + TPB - 1) / TPB;
    int begin = tid * chunk;
    int end = begin + chunk; if (end > N) end = N;
    int s = 0;
    for (int i = begin; i < end; ++i) s += counts[i];
    partial[tid] = s;
    __syncthreads();
    for (int off = 1; off < TPB; off <<= 1) {
        int v = partial[tid];
        int add = (tid >= off) ? partial[tid - off] : 0;
        __syncthreads();
        partial[tid] = v + add;
        __syncthreads();
    }
    int base = (tid == 0) ? 0 : partial[tid - 1];
    for (int i = begin; i < end; ++i) {
        rowptr[i] = base; cursor[i] = base;
        base += counts[i];
    }
    if (tid == TPB - 1) rowptr[N] = base;
}
__global__ void k_fill_fb(const void* ei, const float* __restrict__ ew, int* cursor,
                          int* __restrict__ nbr, float* __restrict__ wgt,
                          int E, const int* flag) {
    int e = blockIdx.x * TPB + threadIdx.x;
    if (e >= E) return;
    int is32 = *flag;
    int r, c; load_rc(ei, e, E, is32, r, c);
    float hw = 0.5f * ew[e];
    int p1 = atomicAdd(&cursor[r], 1);
    nbr[p1] = c; wgt[p1] = hw;
    int p2 = atomicAdd(&cursor[c], 1);
    nbr[p2] = r; wgt[p2] = hw;
}

// ---------------- Z1[N,64] = dis .* (X[N,64] @ W1[64,64]) ----------------
__global__ void k_gemm1(const float* __restrict__ X, const float* __restrict__ W,
                        const float* __restrict__ dis, float* __restrict__ Z, int N) {
    __shared__ float Wl[64 * 64];
    int tid = threadIdx.x;
    #pragma unroll
    for (int i = tid; i < 4096; i += TPB) Wl[i] = W[i];
    __syncthreads();
    int row = blockIdx.x * 4 + (tid >> 6);
    int f = tid & 63;
    if (row >= N) return;
    const float* xr = X + row * 64;
    float s = 0.f;
    #pragma unroll
    for (int k = 0; k < 64; ++k) s = fmaf(xr[k], Wl[k * 64 + f], s);
    Z[row * 64 + f] = dis[row] * s;
}

// ---------------- gather: out[n,f] = epi( dis[n]*(Z[n,f] + sum_j w_j Z[nbr_j,f]) + bias[f] ) ----------------
template <int D, bool RELU>
__global__ void k_gather(const float* __restrict__ Z, const int* __restrict__ rowptr,
                         const int* __restrict__ nbr, const float* __restrict__ wgt,
                         const float* __restrict__ dis, const float* __restrict__ bias,
                         float* __restrict__ out, int N) {
    constexpr int NPB = TPB / D;
    int node = blockIdx.x * NPB + threadIdx.x / D;
    int f = threadIdx.x % D;
    if (node >= N) return;
    int j = rowptr[node];
    int jend = rowptr[node + 1];
    float acc = Z[node * D + f];
    int nn = 0; float ww = 0.f;
    if (j < jend) { nn = nbr[j]; ww = wgt[j]; }
    while (j < jend) {
        int cn = nn; float cw = ww;
        ++j;
        if (j < jend) { nn = nbr[j]; ww = wgt[j]; }  // prefetch next index/weight
        acc = fmaf(cw, Z[cn * D + f], acc);
    }
    float v = fmaf(dis[node], acc, bias[f]);
    if (RELU) v = v > 0.f ? v : 0.f;
    out[node * D + f] = v;
}

// ---------------- Z2[N,16] = dis .* (H[N,64] @ W2[64,16]) ----------------
__global__ void k_gemm2(const float* __restrict__ H, const float* __restrict__ W2,
                        const float* __restrict__ dis, float* __restrict__ Z2, int N) {
    __shared__ float Wl[64 * 16];
    int tid = threadIdx.x;
    #pragma unroll
    for (int i = tid; i < 1024; i += TPB) Wl[i] = W2[i];
    __syncthreads();
    int row = blockIdx.x * 16 + (tid >> 4);
    int f = tid & 15;
    if (row >= N) return;
    const float* hr = H + row * 64;
    float s = 0.f;
    #pragma unroll
    for (int k = 0; k < 64; ++k) s = fmaf(hr[k], Wl[k * 16 + f], s);
    Z2[row * 16 + f] = dis[row] * s;
}

extern "C" void kernel_launch(void* const* d_in, const int* in_sizes, int n_in,
                              void* d_out, int out_size, void* d_ws, size_t ws_size,
                              hipStream_t stream) {
    const float* x  = (const float*)d_in[0];
    const float* W1 = (const float*)d_in[1];
    const float* b1 = (const float*)d_in[2];
    const float* W2 = (const float*)d_in[3];
    const float* b2 = (const float*)d_in[4];
    const float* ew = (const float*)d_in[5];
    const void*  ei = d_in[6];

    const int N = in_sizes[0] / 64;   // 16384
    const int E = in_sizes[5];        // 524288
    const int M = 2 * E;              // CSR entries

    char* ws = (char*)d_ws;
    size_t off = 0;
    auto alloc = [&](size_t bytes) -> void* {
        void* p = ws + off;
        off += (bytes + 255) & ~(size_t)255;
        return p;
    };
    int*   flag   = (int*)alloc(256);
    float* dis    = (float*)alloc((size_t)N * 4);
    int*   counts = (int*)alloc((size_t)N * 4);
    int*   rowptr = (int*)alloc(((size_t)N + 1) * 4);
    int*   cursor = (int*)alloc((size_t)N * 4);          // fallback only
    int*   nbr    = (int*)alloc((size_t)M * 4);
    float* wgt    = (float*)alloc((size_t)M * 4);
    float* Z1     = (float*)alloc((size_t)N * 64 * 4);   // also aliases `partial`
    float* H      = (float*)alloc((size_t)N * 64 * 4);
    float* Z2     = (float*)alloc((size_t)N * 16 * 4);
    (void)ws_size; (void)n_in; (void)out_size;

    // partial[HB*N] ints alias Z1 (HB*N*4 = N*64*4 bytes when HB=64); prep
    // finishes before k_gemm1 writes Z1 on the same stream.
    int* partial = (int*)Z1;

    float* out = (float*)d_out;

    k_flag0<<<1, 64, 0, stream>>>(flag);
    k_detect<<<(E + TPB - 1) / TPB, TPB, 0, stream>>>((const int*)ei, E, flag);

    if (N <= NMAX) {
        k_count<<<HB, TPB, 0, stream>>>(ei, E, flag, partial, N);
        k_reduce<<<(N + TPB - 1) / TPB, TPB, 0, stream>>>(partial, counts, N);
        k_scan2<<<1, TPB, 0, stream>>>(counts, rowptr, N);
        k_fill2<<<HB, TPB, 0, stream>>>(ei, ew, flag, rowptr, partial, nbr, wgt, E, N);
        k_deg_dis<<<(N * 64 + TPB - 1) / TPB, TPB, 0, stream>>>(rowptr, wgt, dis, N);
    } else {
        k_init_fb<<<(N + TPB - 1) / TPB, TPB, 0, stream>>>(dis, counts, N);
        k_deg_cnt_fb<<<(E + TPB - 1) / TPB, TPB, 0, stream>>>(ei, ew, dis, counts, E, flag);
        k_rsqrt_fb<<<(N + TPB - 1) / TPB, TPB, 0, stream>>>(dis, N);
        k_scan_fb<<<1, TPB, 0, stream>>>(counts, rowptr, cursor, N);
        k_fill_fb<<<(E + TPB - 1) / TPB, TPB, 0, stream>>>(ei, ew, cursor, nbr, wgt, E, flag);
    }

    // layer 1
    k_gemm1<<<(N + 3) / 4, TPB, 0, stream>>>(x, W1, dis, Z1, N);
    k_gather<64, true><<<(N + 3) / 4, TPB, 0, stream>>>(Z1, rowptr, nbr, wgt, dis, b1, H, N);

    // layer 2
    k_gemm2<<<(N + 15) / 16, TPB, 0, stream>>>(H, W2, dis, Z2, N);
    k_gather<16, false><<<(N + 15) / 16, TPB, 0, stream>>>(Z2, rowptr, nbr, wgt, dis, b2, out, N);
}

// Round 4
// 265.797 us; speedup vs baseline: 2.0150x; 1.3697x over previous
//
#include <hip/hip_runtime.h>

constexpr int TPB = 256;
constexpr int HB  = 128;     // histogram/fill blocks (partial aliases Z1+H = 8 MB)
constexpr int NMAX = 16384;  // LDS histogram capacity (ints -> 64 KB)

// ---------------- detect edge_index dtype (int64 vs int32), no global atomics ----
// Scans odd int32 words of the first 2E words via int4 loads. int64 layout:
// all odd words are zero high-words (ids < 2^31). int32 layout: odd words are
// node ids. Per-block result -> blockflag[b]; k_flagor OR-reduces into flag.
__global__ void k_detect(const int4* __restrict__ ei4, int nvec, int* __restrict__ bf) {
    __shared__ int any;
    if (threadIdx.x == 0) any = 0;
    __syncthreads();
    int t = blockIdx.x * TPB + threadIdx.x;
    int v = 0;
    if (t < nvec) { int4 q = ei4[t]; v = q.y | q.w; }
    unsigned long long b = __ballot(v != 0);
    if ((threadIdx.x & 63) == 0 && b != 0ULL) any = 1;
    __syncthreads();
    if (threadIdx.x == 0) bf[blockIdx.x] = any;
}

__global__ void k_flagor(const int* __restrict__ bf, int nb,
                         const int* __restrict__ ei32, int totwords, int nvec,
                         int* __restrict__ flag) {
    __shared__ int any;
    if (threadIdx.x == 0) any = 0;
    __syncthreads();
    int s = 0;
    for (int i = threadIdx.x; i < nb; i += TPB) s |= bf[i];
    if (threadIdx.x == 0) {  // tail words not covered by int4 scan
        for (int w = 4 * nvec + 1; w < totwords; w += 2) s |= ei32[w];
    }
    if (s) atomicOr(&any, 1);   // LDS atomic, cheap
    __syncthreads();
    if (threadIdx.x == 0) *flag = any ? 1 : 0;
}

__device__ __forceinline__ void load_rc(const void* ei, int e, int E, int is32,
                                        int& r, int& c) {
    if (is32) {
        const int* p = (const int*)ei;
        r = p[e]; c = p[E + e];
    } else {
        const long long* p = (const long long*)ei;
        r = (int)p[e]; c = (int)p[E + e];
    }
}

// ---------------- pass A: per-block LDS histogram of endpoint counts ----------------
__global__ void k_count(const void* ei, int E, const int* flag,
                        int* __restrict__ partial, int N) {
    __shared__ int cnt[NMAX];
    for (int i = threadIdx.x; i < N; i += TPB) cnt[i] = 0;
    __syncthreads();
    int is32 = *flag;
    int chunk = (E + HB - 1) / HB;
    int b = blockIdx.x;
    int e0 = b * chunk;
    int e1 = e0 + chunk; if (e1 > E) e1 = E;
    for (int e = e0 + threadIdx.x; e < e1; e += TPB) {
        int r, c; load_rc(ei, e, E, is32, r, c);
        atomicAdd(&cnt[r], 1);
        atomicAdd(&cnt[c], 1);
    }
    __syncthreads();
    for (int i = threadIdx.x; i < N; i += TPB) partial[b * N + i] = cnt[i];
}

// ---------------- pass B: per-node exclusive prefix over blocks (in place) ----------------
__global__ void k_reduce(int* __restrict__ partial, int* __restrict__ counts, int N) {
    int i = blockIdx.x * TPB + threadIdx.x;
    if (i >= N) return;
    int run = 0;
    for (int b = 0; b < HB; ++b) {
        int v = partial[b * N + i];
        partial[b * N + i] = run;
        run += v;
    }
    counts[i] = run;
}

// ---------------- pass C: exclusive scan counts -> rowptr (LDS-staged) ----------------
__global__ void k_scan2(const int* __restrict__ counts, int* __restrict__ rowptr, int N) {
    __shared__ int v[NMAX];
    __shared__ int part[TPB];
    int tid = threadIdx.x;
    for (int i = tid; i < N; i += TPB) v[i] = counts[i];
    __syncthreads();
    int chunk = (N + TPB - 1) / TPB;
    int b0 = tid * chunk;
    int b1 = b0 + chunk; if (b1 > N) b1 = N;
    int s = 0;
    for (int i = b0; i < b1; ++i) s += v[i];
    part[tid] = s;
    __syncthreads();
    for (int off = 1; off < TPB; off <<= 1) {
        int t = part[tid];
        int add = (tid >= off) ? part[tid - off] : 0;
        __syncthreads();
        part[tid] = t + add;
        __syncthreads();
    }
    int base = (tid == 0) ? 0 : part[tid - 1];
    for (int i = b0; i < b1; ++i) { int t = v[i]; v[i] = base; base += t; }
    __syncthreads();
    for (int i = tid; i < N; i += TPB) rowptr[i] = v[i];
    if (tid == TPB - 1) rowptr[N] = part[TPB - 1];
}

// ---------------- pass D: CSR fill with LDS cursors (no global atomics) ----------------
__global__ void k_fill2(const void* ei, const float* __restrict__ ew, const int* flag,
                        const int* __restrict__ rowptr, const int* __restrict__ partial,
                        int* __restrict__ nbr, float* __restrict__ wgt, int E, int N) {
    __shared__ int cur[NMAX];
    int b = blockIdx.x;
    for (int i = threadIdx.x; i < N; i += TPB) cur[i] = rowptr[i] + partial[b * N + i];
    __syncthreads();
    int is32 = *flag;
    int chunk = (E + HB - 1) / HB;
    int e0 = b * chunk;
    int e1 = e0 + chunk; if (e1 > E) e1 = E;
    for (int e = e0 + threadIdx.x; e < e1; e += TPB) {
        int r, c; load_rc(ei, e, E, is32, r, c);
        float hw = 0.5f * ew[e];
        int p1 = atomicAdd(&cur[r], 1);
        nbr[p1] = c; wgt[p1] = hw;
        int p2 = atomicAdd(&cur[c], 1);
        nbr[p2] = r; wgt[p2] = hw;
    }
}

// ---------------- pass E: dis[i] = rsqrt(1 + sum(wgt row i)), wave per node ----------------
__global__ void k_deg_dis(const int* __restrict__ rowptr, const float* __restrict__ wgt,
                          float* __restrict__ dis, int N) {
    int wv = (blockIdx.x * TPB + threadIdx.x) >> 6;
    int lane = threadIdx.x & 63;
    if (wv >= N) return;
    int j0 = rowptr[wv], j1 = rowptr[wv + 1];
    float s = 0.f;
    for (int j = j0 + lane; j < j1; j += 64) s += wgt[j];
    #pragma unroll
    for (int off = 32; off; off >>= 1) s += __shfl_down(s, off, 64);
    if (lane == 0) dis[wv] = rsqrtf(1.f + s);
}

// ============ fallback path (N > NMAX): global-atomic prep ============
__global__ void k_init_fb(float* deg, int* counts, int N) {
    int i = blockIdx.x * TPB + threadIdx.x;
    if (i < N) { deg[i] = 1.0f; counts[i] = 0; }
}
__global__ void k_deg_cnt_fb(const void* ei, const float* __restrict__ ew,
                             float* deg, int* counts, int E, const int* flag) {
    int e = blockIdx.x * TPB + threadIdx.x;
    if (e >= E) return;
    int is32 = *flag;
    int r, c; load_rc(ei, e, E, is32, r, c);
    float hw = 0.5f * ew[e];
    unsafeAtomicAdd(&deg[r], hw);
    unsafeAtomicAdd(&deg[c], hw);
    atomicAdd(&counts[r], 1);
    atomicAdd(&counts[c], 1);
}
__global__ void k_rsqrt_fb(float* degdis, int N) {
    int i = blockIdx.x * TPB + threadIdx.x;
    if (i < N) {
        float d = degdis[i];
        degdis[i] = d > 0.f ? rsqrtf(d) : 0.f;
    }
}
__global__ void k_scan_fb(const int* __restrict__ counts, int* __restrict__ rowptr,
                          int* __restrict__ cursor, int N) {
    __shared__ int partial[TPB];
    int tid = threadIdx.x;
    int chunk = (N + TPB - 1) / TPB;
    int begin = tid * chunk;
    int end = begin + chunk; if (end > N) end = N;
    int s = 0;
    for (int i = begin; i < end; ++i) s += counts[i];
    partial[tid] = s;
    __syncthreads();
    for (int off = 1; off < TPB; off <<= 1) {
        int v = partial[tid];
        int add = (tid >= off) ? partial[tid - off] : 0;
        __syncthreads();
        partial[tid] = v + add;
        __syncthreads();
    }
    int base = (tid == 0) ? 0 : partial[tid - 1];
    for (int i = begin; i < end; ++i) {
        rowptr[i] = base; cursor[i] = base;
        base += counts[i];
    }
    if (tid == TPB - 1) rowptr[N] = base;
}
__global__ void k_fill_fb(const void* ei, const float* __restrict__ ew, int* cursor,
                          int* __restrict__ nbr, float* __restrict__ wgt,
                          int E, const int* flag) {
    int e = blockIdx.x * TPB + threadIdx.x;
    if (e >= E) return;
    int is32 = *flag;
    int r, c; load_rc(ei, e, E, is32, r, c);
    float hw = 0.5f * ew[e];
    int p1 = atomicAdd(&cursor[r], 1);
    nbr[p1] = c; wgt[p1] = hw;
    int p2 = atomicAdd(&cursor[c], 1);
    nbr[p2] = r; wgt[p2] = hw;
}

// ---------------- Z1[N,64] = dis .* (X[N,64] @ W1[64,64]) ----------------
__global__ void k_gemm1(const float* __restrict__ X, const float* __restrict__ W,
                        const float* __restrict__ dis, float* __restrict__ Z, int N) {
    __shared__ float Wl[64 * 64];
    int tid = threadIdx.x;
    #pragma unroll
    for (int i = tid; i < 4096; i += TPB) Wl[i] = W[i];
    __syncthreads();
    int row = blockIdx.x * 4 + (tid >> 6);
    int f = tid & 63;
    if (row >= N) return;
    const float* xr = X + row * 64;
    float s = 0.f;
    #pragma unroll
    for (int k = 0; k < 64; ++k) s = fmaf(xr[k], Wl[k * 64 + f], s);
    Z[row * 64 + f] = dis[row] * s;
}

// ---------------- gather: out[n,f] = epi( dis[n]*(Z[n,f] + sum_j w_j Z[nbr_j,f]) + bias[f] ) ----------------
template <int D, bool RELU>
__global__ void k_gather(const float* __restrict__ Z, const int* __restrict__ rowptr,
                         const int* __restrict__ nbr, const float* __restrict__ wgt,
                         const float* __restrict__ dis, const float* __restrict__ bias,
                         float* __restrict__ out, int N) {
    constexpr int NPB = TPB / D;
    int node = blockIdx.x * NPB + threadIdx.x / D;
    int f = threadIdx.x % D;
    if (node >= N) return;
    int j = rowptr[node];
    int jend = rowptr[node + 1];
    float acc = Z[node * D + f];
    // 2-way unroll: two independent gathered loads in flight per iteration
    for (; j + 2 <= jend; j += 2) {
        int n0 = nbr[j];     float w0 = wgt[j];
        int n1 = nbr[j + 1]; float w1 = wgt[j + 1];
        float z0 = Z[n0 * D + f];
        float z1 = Z[n1 * D + f];
        acc = fmaf(w0, z0, acc);
        acc = fmaf(w1, z1, acc);
    }
    if (j < jend) acc = fmaf(wgt[j], Z[nbr[j] * D + f], acc);
    float v = fmaf(dis[node], acc, bias[f]);
    if (RELU) v = v > 0.f ? v : 0.f;
    out[node * D + f] = v;
}

// ---------------- Z2[N,16] = dis .* (H[N,64] @ W2[64,16]) ----------------
__global__ void k_gemm2(const float* __restrict__ H, const float* __restrict__ W2,
                        const float* __restrict__ dis, float* __restrict__ Z2, int N) {
    __shared__ float Wl[64 * 16];
    int tid = threadIdx.x;
    #pragma unroll
    for (int i = tid; i < 1024; i += TPB) Wl[i] = W2[i];
    __syncthreads();
    int row = blockIdx.x * 16 + (tid >> 4);
    int f = tid & 15;
    if (row >= N) return;
    const float* hr = H + row * 64;
    float s = 0.f;
    #pragma unroll
    for (int k = 0; k < 64; ++k) s = fmaf(hr[k], Wl[k * 16 + f], s);
    Z2[row * 16 + f] = dis[row] * s;
}

extern "C" void kernel_launch(void* const* d_in, const int* in_sizes, int n_in,
                              void* d_out, int out_size, void* d_ws, size_t ws_size,
                              hipStream_t stream) {
    const float* x  = (const float*)d_in[0];
    const float* W1 = (const float*)d_in[1];
    const float* b1 = (const float*)d_in[2];
    const float* W2 = (const float*)d_in[3];
    const float* b2 = (const float*)d_in[4];
    const float* ew = (const float*)d_in[5];
    const void*  ei = d_in[6];

    const int N = in_sizes[0] / 64;   // 16384
    const int E = in_sizes[5];        // 524288
    const int M = 2 * E;              // CSR entries

    char* ws = (char*)d_ws;
    size_t off = 0;
    auto alloc = [&](size_t bytes) -> void* {
        void* p = ws + off;
        off += (bytes + 255) & ~(size_t)255;
        return p;
    };
    int*   flag   = (int*)alloc(256);
    float* dis    = (float*)alloc((size_t)N * 4);
    int*   counts = (int*)alloc((size_t)N * 4);
    int*   rowptr = (int*)alloc(((size_t)N + 1) * 4);
    int*   cursor = (int*)alloc((size_t)N * 4);          // fallback cursor; also detect blockflags
    int*   nbr    = (int*)alloc((size_t)M * 4);
    float* wgt    = (float*)alloc((size_t)M * 4);
    float* Z1     = (float*)alloc((size_t)N * 64 * 4);   // partial aliases Z1+H (8 MB)
    float* H      = (float*)alloc((size_t)N * 64 * 4);
    float* Z2     = (float*)alloc((size_t)N * 16 * 4);
    (void)ws_size; (void)n_in; (void)out_size;

    // partial[HB*N] ints alias Z1+H (HB=128 -> 8 MB); prep finishes before
    // k_gemm1/k_gather write Z1/H on the same stream.
    int* partial = (int*)Z1;

    float* out = (float*)d_out;

    // dtype detection: int4 scan -> per-block flags (in `cursor`) -> OR-reduce
    const int totwords = 2 * E;
    const int nvec = totwords / 4;
    const int nb = (nvec + TPB - 1) / TPB;
    k_detect<<<nb, TPB, 0, stream>>>((const int4*)ei, nvec, cursor);
    k_flagor<<<1, TPB, 0, stream>>>(cursor, nb, (const int*)ei, totwords, nvec, flag);

    if (N <= NMAX) {
        k_count<<<HB, TPB, 0, stream>>>(ei, E, flag, partial, N);
        k_reduce<<<(N + TPB - 1) / TPB, TPB, 0, stream>>>(partial, counts, N);
        k_scan2<<<1, TPB, 0, stream>>>(counts, rowptr, N);
        k_fill2<<<HB, TPB, 0, stream>>>(ei, ew, flag, rowptr, partial, nbr, wgt, E, N);
        k_deg_dis<<<(N * 64 + TPB - 1) / TPB, TPB, 0, stream>>>(rowptr, wgt, dis, N);
    } else {
        k_init_fb<<<(N + TPB - 1) / TPB, TPB, 0, stream>>>(dis, counts, N);
        k_deg_cnt_fb<<<(E + TPB - 1) / TPB, TPB, 0, stream>>>(ei, ew, dis, counts, E, flag);
        k_rsqrt_fb<<<(N + TPB - 1) / TPB, TPB, 0, stream>>>(dis, N);
        k_scan_fb<<<1, TPB, 0, stream>>>(counts, rowptr, cursor, N);
        k_fill_fb<<<(E + TPB - 1) / TPB, TPB, 0, stream>>>(ei, ew, cursor, nbr, wgt, E, flag);
    }

    // layer 1
    k_gemm1<<<(N + 3) / 4, TPB, 0, stream>>>(x, W1, dis, Z1, N);
    k_gather<64, true><<<(N + 3) / 4, TPB, 0, stream>>>(Z1, rowptr, nbr, wgt, dis, b1, H, N);

    // layer 2
    k_gemm2<<<(N + 15) / 16, TPB, 0, stream>>>(H, W2, dis, Z2, N);
    k_gather<16, false><<<(N + 15) / 16, TPB, 0, stream>>>(Z2, rowptr, nbr, wgt, dis, b2, out, N);
}

// Round 5
// 237.387 us; speedup vs baseline: 2.2561x; 1.1197x over previous
//
#include <hip/hip_runtime.h>

constexpr int TPB = 256;
constexpr int HB  = 256;     // histogram/fill blocks; partial (u16-packed) aliases Z1+H = 8 MB
constexpr int NMAX = 16384;  // LDS histogram capacity (ints -> 64 KB)

// ---------------- detect edge_index dtype (int64 vs int32), no global atomics ----
__global__ void k_detect(const int4* __restrict__ ei4, int nvec, int* __restrict__ bf) {
    __shared__ int any;
    if (threadIdx.x == 0) any = 0;
    __syncthreads();
    int t = blockIdx.x * TPB + threadIdx.x;
    int v = 0;
    if (t < nvec) { int4 q = ei4[t]; v = q.y | q.w; }
    unsigned long long b = __ballot(v != 0);
    if ((threadIdx.x & 63) == 0 && b != 0ULL) any = 1;
    __syncthreads();
    if (threadIdx.x == 0) bf[blockIdx.x] = any;
}

__global__ void k_flagor(const int* __restrict__ bf, int nb,
                         const int* __restrict__ ei32, int totwords, int nvec,
                         int* __restrict__ flag) {
    __shared__ int any;
    if (threadIdx.x == 0) any = 0;
    __syncthreads();
    int s = 0;
    for (int i = threadIdx.x; i < nb; i += TPB) s |= bf[i];
    if (threadIdx.x == 0) {
        for (int w = 4 * nvec + 1; w < totwords; w += 2) s |= ei32[w];
    }
    if (s) atomicOr(&any, 1);
    __syncthreads();
    if (threadIdx.x == 0) *flag = any ? 1 : 0;
}

__device__ __forceinline__ void load_rc(const void* ei, int e, int E, int is32,
                                        int& r, int& c) {
    if (is32) {
        const int* p = (const int*)ei;
        r = p[e]; c = p[E + e];
    } else {
        const long long* p = (const long long*)ei;
        r = (int)p[e]; c = (int)p[E + e];
    }
}

// ---------------- pass A: per-block LDS histogram -> u16-packed partial ----------------
__global__ void k_count(const void* ei, int E, const int* flag,
                        unsigned* __restrict__ partialU, int N) {
    __shared__ int cnt[NMAX];
    for (int i = threadIdx.x; i < N; i += TPB) cnt[i] = 0;
    __syncthreads();
    int is32 = *flag;
    int chunk = (E + HB - 1) / HB;
    int b = blockIdx.x;
    int e0 = b * chunk;
    int e1 = e0 + chunk; if (e1 > E) e1 = E;
    for (int e = e0 + threadIdx.x; e < e1; e += TPB) {
        int r, c; load_rc(ei, e, E, is32, r, c);
        atomicAdd(&cnt[r], 1);
        atomicAdd(&cnt[c], 1);
    }
    __syncthreads();
    int halfN = (N + 1) >> 1;
    for (int i = threadIdx.x; i < halfN; i += TPB) {
        unsigned c0 = (unsigned)cnt[2 * i] & 0xFFFFu;
        unsigned c1 = (2 * i + 1 < N) ? ((unsigned)cnt[2 * i + 1] & 0xFFFFu) : 0u;
        partialU[(size_t)b * halfN + i] = c0 | (c1 << 16);
    }
}

// ---------------- pass B: per-node exclusive prefix over blocks (in place, pairs) ----------------
__global__ void k_reduce(unsigned* __restrict__ partialU, int* __restrict__ counts, int N) {
    int halfN = (N + 1) >> 1;
    int i = blockIdx.x * TPB + threadIdx.x;
    if (i >= halfN) return;
    int run0 = 0, run1 = 0;
    for (int b = 0; b < HB; ++b) {
        size_t idx = (size_t)b * halfN + i;
        unsigned v = partialU[idx];
        partialU[idx] = ((unsigned)run0 & 0xFFFFu) | (((unsigned)run1 & 0xFFFFu) << 16);
        run0 += (int)(v & 0xFFFFu);
        run1 += (int)(v >> 16);
    }
    counts[2 * i] = run0;
    if (2 * i + 1 < N) counts[2 * i + 1] = run1;
}

// ---------------- pass C: exclusive scan counts -> rowptr (LDS-staged) ----------------
__global__ void k_scan2(const int* __restrict__ counts, int* __restrict__ rowptr, int N) {
    __shared__ int v[NMAX];
    __shared__ int part[TPB];
    int tid = threadIdx.x;
    for (int i = tid; i < N; i += TPB) v[i] = counts[i];
    __syncthreads();
    int chunk = (N + TPB - 1) / TPB;
    int b0 = tid * chunk;
    int b1 = b0 + chunk; if (b1 > N) b1 = N;
    int s = 0;
    for (int i = b0; i < b1; ++i) s += v[i];
    part[tid] = s;
    __syncthreads();
    for (int off = 1; off < TPB; off <<= 1) {
        int t = part[tid];
        int add = (tid >= off) ? part[tid - off] : 0;
        __syncthreads();
        part[tid] = t + add;
        __syncthreads();
    }
    int base = (tid == 0) ? 0 : part[tid - 1];
    for (int i = b0; i < b1; ++i) { int t = v[i]; v[i] = base; base += t; }
    __syncthreads();
    for (int i = tid; i < N; i += TPB) rowptr[i] = v[i];
    if (tid == TPB - 1) rowptr[N] = part[TPB - 1];
}

// ---------------- pass D: CSR fill, packed int2 entries, LDS cursors ----------------
__global__ void k_fill2(const void* ei, const float* __restrict__ ew, const int* flag,
                        const int* __restrict__ rowptr, const unsigned* __restrict__ partialU,
                        int2* __restrict__ ent, int E, int N) {
    __shared__ int cur[NMAX];
    int b = blockIdx.x;
    int halfN = (N + 1) >> 1;
    for (int i = threadIdx.x; i < halfN; i += TPB) {
        unsigned v = partialU[(size_t)b * halfN + i];
        cur[2 * i] = rowptr[2 * i] + (int)(v & 0xFFFFu);
        if (2 * i + 1 < N) cur[2 * i + 1] = rowptr[2 * i + 1] + (int)(v >> 16);
    }
    __syncthreads();
    int is32 = *flag;
    int chunk = (E + HB - 1) / HB;
    int e0 = b * chunk;
    int e1 = e0 + chunk; if (e1 > E) e1 = E;
    for (int e = e0 + threadIdx.x; e < e1; e += TPB) {
        int r, c; load_rc(ei, e, E, is32, r, c);
        int hw = __float_as_int(0.5f * ew[e]);
        int p1 = atomicAdd(&cur[r], 1);
        ent[p1] = make_int2(c, hw);
        int p2 = atomicAdd(&cur[c], 1);
        ent[p2] = make_int2(r, hw);
    }
}

// ---------------- pass E: dis[i] = rsqrt(1 + sum(wgt row i)), wave per node ----------------
__global__ void k_deg_dis(const int* __restrict__ rowptr, const int2* __restrict__ ent,
                          float* __restrict__ dis, int N) {
    int wv = (blockIdx.x * TPB + threadIdx.x) >> 6;
    int lane = threadIdx.x & 63;
    if (wv >= N) return;
    int j0 = rowptr[wv], j1 = rowptr[wv + 1];
    float s = 0.f;
    for (int j = j0 + lane; j < j1; j += 64) s += __int_as_float(ent[j].y);
    #pragma unroll
    for (int off = 32; off; off >>= 1) s += __shfl_down(s, off, 64);
    if (lane == 0) dis[wv] = rsqrtf(1.f + s);
}

// ============ fallback path (N > NMAX): global-atomic prep ============
__global__ void k_init_fb(float* deg, int* counts, int N) {
    int i = blockIdx.x * TPB + threadIdx.x;
    if (i < N) { deg[i] = 1.0f; counts[i] = 0; }
}
__global__ void k_deg_cnt_fb(const void* ei, const float* __restrict__ ew,
                             float* deg, int* counts, int E, const int* flag) {
    int e = blockIdx.x * TPB + threadIdx.x;
    if (e >= E) return;
    int is32 = *flag;
    int r, c; load_rc(ei, e, E, is32, r, c);
    float hw = 0.5f * ew[e];
    unsafeAtomicAdd(&deg[r], hw);
    unsafeAtomicAdd(&deg[c], hw);
    atomicAdd(&counts[r], 1);
    atomicAdd(&counts[c], 1);
}
__global__ void k_rsqrt_fb(float* degdis, int N) {
    int i = blockIdx.x * TPB + threadIdx.x;
    if (i < N) {
        float d = degdis[i];
        degdis[i] = d > 0.f ? rsqrtf(d) : 0.f;
    }
}
__global__ void k_scan_fb(const int* __restrict__ counts, int* __restrict__ rowptr,
                          int* __restrict__ cursor, int N) {
    __shared__ int partial[TPB];
    int tid = threadIdx.x;
    int chunk = (N + TPB - 1) / TPB;
    int begin = tid * chunk;
    int end = begin + chunk; if (end > N) end = N;
    int s = 0;
    for (int i = begin; i < end; ++i) s += counts[i];
    partial[tid] = s;
    __syncthreads();
    for (int off = 1; off < TPB; off <<= 1) {
        int v = partial[tid];
        int add = (tid >= off) ? partial[tid - off] : 0;
        __syncthreads();
        partial[tid] = v + add;
        __syncthreads();
    }
    int base = (tid == 0) ? 0 : partial[tid - 1];
    for (int i = begin; i < end; ++i) {
        rowptr[i] = base; cursor[i] = base;
        base += counts[i];
    }
    if (tid == TPB - 1) rowptr[N] = base;
}
__global__ void k_fill_fb(const void* ei, const float* __restrict__ ew, int* cursor,
                          int2* __restrict__ ent, int E, const int* flag) {
    int e = blockIdx.x * TPB + threadIdx.x;
    if (e >= E) return;
    int is32 = *flag;
    int r, c; load_rc(ei, e, E, is32, r, c);
    int hw = __float_as_int(0.5f * ew[e]);
    int p1 = atomicAdd(&cursor[r], 1);
    ent[p1] = make_int2(c, hw);
    int p2 = atomicAdd(&cursor[c], 1);
    ent[p2] = make_int2(r, hw);
}

// ---------------- Z1[N,64] = dis .* (X[N,64] @ W1[64,64]) ----------------
__global__ void k_gemm1(const float* __restrict__ X, const float* __restrict__ W,
                        const float* __restrict__ dis, float* __restrict__ Z, int N) {
    __shared__ float Wl[64 * 64];
    int tid = threadIdx.x;
    #pragma unroll
    for (int i = tid; i < 4096; i += TPB) Wl[i] = W[i];
    __syncthreads();
    int row = blockIdx.x * 4 + (tid >> 6);
    int f = tid & 63;
    if (row >= N) return;
    const float* xr = X + row * 64;
    float s = 0.f;
    #pragma unroll
    for (int k = 0; k < 64; ++k) s = fmaf(xr[k], Wl[k * 64 + f], s);
    Z[row * 64 + f] = dis[row] * s;
}

// ---------------- gather: cooperative entry load + shuffle broadcast + 4-way MLP ----
template <int D, bool RELU>
__global__ void k_gather(const float* __restrict__ Z, const int* __restrict__ rowptr,
                         const int2* __restrict__ ent, const float* __restrict__ dis,
                         const float* __restrict__ bias, float* __restrict__ out,
                         int N, int M) {
    constexpr int NPB = TPB / D;
    int node = blockIdx.x * NPB + threadIdx.x / D;
    int f = threadIdx.x % D;
    int lane = threadIdx.x & 63;
    int base = lane & ~(D - 1);  // group base lane within the wave
    if (node >= N) return;
    int j0 = rowptr[node], j1 = rowptr[node + 1];
    float acc = Z[node * D + f];
    for (int jb = j0; jb < j1; jb += D) {
        int idx = jb + f; if (idx >= M) idx = M - 1;   // clamp (garbage lanes unused)
        int2 e = ent[idx];                              // coalesced cooperative load
        int cnt = j1 - jb; if (cnt > D) cnt = D;
        int k = 0;
        for (; k + 4 <= cnt; k += 4) {
            int n0 = __shfl(e.x, base + k);     float w0 = __int_as_float(__shfl(e.y, base + k));
            int n1 = __shfl(e.x, base + k + 1); float w1 = __int_as_float(__shfl(e.y, base + k + 1));
            int n2 = __shfl(e.x, base + k + 2); float w2 = __int_as_float(__shfl(e.y, base + k + 2));
            int n3 = __shfl(e.x, base + k + 3); float w3 = __int_as_float(__shfl(e.y, base + k + 3));
            float z0 = Z[n0 * D + f];
            float z1 = Z[n1 * D + f];
            float z2 = Z[n2 * D + f];
            float z3 = Z[n3 * D + f];
            acc = fmaf(w0, z0, acc);
            acc = fmaf(w1, z1, acc);
            acc = fmaf(w2, z2, acc);
            acc = fmaf(w3, z3, acc);
        }
        for (; k < cnt; ++k) {
            int n0 = __shfl(e.x, base + k);
            float w0 = __int_as_float(__shfl(e.y, base + k));
            acc = fmaf(w0, Z[n0 * D + f], acc);
        }
    }
    float v = fmaf(dis[node], acc, bias[f]);
    if (RELU) v = v > 0.f ? v : 0.f;
    out[node * D + f] = v;
}

// ---------------- Z2[N,16] = dis .* (H[N,64] @ W2[64,16]) ----------------
__global__ void k_gemm2(const float* __restrict__ H, const float* __restrict__ W2,
                        const float* __restrict__ dis, float* __restrict__ Z2, int N) {
    __shared__ float Wl[64 * 16];
    int tid = threadIdx.x;
    #pragma unroll
    for (int i = tid; i < 1024; i += TPB) Wl[i] = W2[i];
    __syncthreads();
    int row = blockIdx.x * 16 + (tid >> 4);
    int f = tid & 15;
    if (row >= N) return;
    const float* hr = H + row * 64;
    float s = 0.f;
    #pragma unroll
    for (int k = 0; k < 64; ++k) s = fmaf(hr[k], Wl[k * 16 + f], s);
    Z2[row * 16 + f] = dis[row] * s;
}

extern "C" void kernel_launch(void* const* d_in, const int* in_sizes, int n_in,
                              void* d_out, int out_size, void* d_ws, size_t ws_size,
                              hipStream_t stream) {
    const float* x  = (const float*)d_in[0];
    const float* W1 = (const float*)d_in[1];
    const float* b1 = (const float*)d_in[2];
    const float* W2 = (const float*)d_in[3];
    const float* b2 = (const float*)d_in[4];
    const float* ew = (const float*)d_in[5];
    const void*  ei = d_in[6];

    const int N = in_sizes[0] / 64;   // 16384
    const int E = in_sizes[5];        // 524288
    const int M = 2 * E;              // CSR entries

    char* ws = (char*)d_ws;
    size_t off = 0;
    auto alloc = [&](size_t bytes) -> void* {
        void* p = ws + off;
        off += (bytes + 255) & ~(size_t)255;
        return p;
    };
    int*   flag   = (int*)alloc(256);
    float* dis    = (float*)alloc((size_t)N * 4);
    int*   counts = (int*)alloc((size_t)N * 4);
    int*   rowptr = (int*)alloc(((size_t)N + 1) * 4);
    int*   cursor = (int*)alloc((size_t)N * 4);          // fallback cursor; also detect blockflags
    int2*  ent    = (int2*)alloc((size_t)M * 8);         // packed (nbr, wgt_bits)
    float* Z1     = (float*)alloc((size_t)N * 64 * 4);   // partial aliases Z1+H (8 MB)
    float* H      = (float*)alloc((size_t)N * 64 * 4);
    float* Z2     = (float*)alloc((size_t)N * 16 * 4);
    (void)ws_size; (void)n_in; (void)out_size;

    // partialU[HB * ceil(N/2)] uints alias Z1+H (HB=256 -> 8 MB); prep finishes
    // before k_gemm1/k_gather write Z1/H on the same stream.
    unsigned* partialU = (unsigned*)Z1;

    float* out = (float*)d_out;

    // dtype detection: int4 scan -> per-block flags (in `cursor`) -> OR-reduce
    const int totwords = 2 * E;
    const int nvec = totwords / 4;
    const int nb = (nvec + TPB - 1) / TPB;
    k_detect<<<nb, TPB, 0, stream>>>((const int4*)ei, nvec, cursor);
    k_flagor<<<1, TPB, 0, stream>>>(cursor, nb, (const int*)ei, totwords, nvec, flag);

    if (N <= NMAX) {
        const int halfN = (N + 1) >> 1;
        k_count<<<HB, TPB, 0, stream>>>(ei, E, flag, partialU, N);
        k_reduce<<<(halfN + TPB - 1) / TPB, TPB, 0, stream>>>(partialU, counts, N);
        k_scan2<<<1, TPB, 0, stream>>>(counts, rowptr, N);
        k_fill2<<<HB, TPB, 0, stream>>>(ei, ew, flag, rowptr, partialU, ent, E, N);
        k_deg_dis<<<(N * 64 + TPB - 1) / TPB, TPB, 0, stream>>>(rowptr, ent, dis, N);
    } else {
        k_init_fb<<<(N + TPB - 1) / TPB, TPB, 0, stream>>>(dis, counts, N);
        k_deg_cnt_fb<<<(E + TPB - 1) / TPB, TPB, 0, stream>>>(ei, ew, dis, counts, E, flag);
        k_rsqrt_fb<<<(N + TPB - 1) / TPB, TPB, 0, stream>>>(dis, N);
        k_scan_fb<<<1, TPB, 0, stream>>>(counts, rowptr, cursor, N);
        k_fill_fb<<<(E + TPB - 1) / TPB, TPB, 0, stream>>>(ei, ew, cursor, ent, E, flag);
    }

    // layer 1
    k_gemm1<<<(N + 3) / 4, TPB, 0, stream>>>(x, W1, dis, Z1, N);
    k_gather<64, true><<<(N + 3) / 4, TPB, 0, stream>>>(Z1, rowptr, ent, dis, b1, H, N, M);

    // layer 2
    k_gemm2<<<(N + 15) / 16, TPB, 0, stream>>>(H, W2, dis, Z2, N);
    k_gather<16, false><<<(N + 15) / 16, TPB, 0, stream>>>(Z2, rowptr, ent, dis, b2, out, N, M);
}

// Round 6
// 219.394 us; speedup vs baseline: 2.4411x; 1.0820x over previous
//
#include <hip/hip_runtime.h>

constexpr int TPB  = 256;    // generic block
constexpr int TPBH = 1024;   // histogram/fill block (16 waves to hide scatter latency)
constexpr int HB   = 256;    // histogram/fill grid; u16-packed partial aliases Z1+H = 8 MB
constexpr int NMAX = 16384;  // LDS histogram capacity (ints -> 64 KB)

// edge_index is delivered by this harness as int32 [2][E].
// Evidence (round 3 counters): the dtype-probe atomic fired on ALL 8192 waves,
// i.e. odd int32 words are nonzero everywhere -> int32 layout, not int64.
__device__ __forceinline__ void load_rc(const int* __restrict__ p, int e, int E,
                                        int& r, int& c) {
    r = p[e]; c = p[E + e];
}

// ---------------- pass A: per-block LDS histogram -> u16-packed partial ----------------
__global__ void k_count(const int* __restrict__ ei, int E,
                        unsigned* __restrict__ partialU, int N) {
    __shared__ int cnt[NMAX];
    for (int i = threadIdx.x; i < N; i += TPBH) cnt[i] = 0;
    __syncthreads();
    int chunk = (E + HB - 1) / HB;
    int b = blockIdx.x;
    int e0 = b * chunk;
    int e1 = e0 + chunk; if (e1 > E) e1 = E;
    for (int e = e0 + threadIdx.x; e < e1; e += TPBH) {
        int r, c; load_rc(ei, e, E, r, c);
        atomicAdd(&cnt[r], 1);
        atomicAdd(&cnt[c], 1);
    }
    __syncthreads();
    int halfN = (N + 1) >> 1;
    for (int i = threadIdx.x; i < halfN; i += TPBH) {
        unsigned c0 = (unsigned)cnt[2 * i] & 0xFFFFu;
        unsigned c1 = (2 * i + 1 < N) ? ((unsigned)cnt[2 * i + 1] & 0xFFFFu) : 0u;
        partialU[(size_t)b * halfN + i] = c0 | (c1 << 16);
    }
}

// ---------------- pass B: per-node exclusive prefix over blocks (in place, pairs) ----------------
__global__ void k_reduce(unsigned* __restrict__ partialU, int* __restrict__ counts, int N) {
    int halfN = (N + 1) >> 1;
    int i = blockIdx.x * TPB + threadIdx.x;
    if (i >= halfN) return;
    int run0 = 0, run1 = 0;
    for (int b = 0; b < HB; ++b) {
        size_t idx = (size_t)b * halfN + i;
        unsigned v = partialU[idx];
        partialU[idx] = ((unsigned)run0 & 0xFFFFu) | (((unsigned)run1 & 0xFFFFu) << 16);
        run0 += (int)(v & 0xFFFFu);
        run1 += (int)(v >> 16);
    }
    counts[2 * i] = run0;
    if (2 * i + 1 < N) counts[2 * i + 1] = run1;
}

// ---------------- pass C: exclusive scan counts -> rowptr (LDS-staged) ----------------
__global__ void k_scan2(const int* __restrict__ counts, int* __restrict__ rowptr, int N) {
    __shared__ int v[NMAX];
    __shared__ int part[TPB];
    int tid = threadIdx.x;
    for (int i = tid; i < N; i += TPB) v[i] = counts[i];
    __syncthreads();
    int chunk = (N + TPB - 1) / TPB;
    int b0 = tid * chunk;
    int b1 = b0 + chunk; if (b1 > N) b1 = N;
    int s = 0;
    for (int i = b0; i < b1; ++i) s += v[i];
    part[tid] = s;
    __syncthreads();
    for (int off = 1; off < TPB; off <<= 1) {
        int t = part[tid];
        int add = (tid >= off) ? part[tid - off] : 0;
        __syncthreads();
        part[tid] = t + add;
        __syncthreads();
    }
    int base = (tid == 0) ? 0 : part[tid - 1];
    for (int i = b0; i < b1; ++i) { int t = v[i]; v[i] = base; base += t; }
    __syncthreads();
    for (int i = tid; i < N; i += TPB) rowptr[i] = v[i];
    if (tid == TPB - 1) rowptr[N] = part[TPB - 1];
}

// ---------------- pass D: CSR fill, packed int2 entries, LDS cursors ----------------
__global__ void k_fill2(const int* __restrict__ ei, const float* __restrict__ ew,
                        const int* __restrict__ rowptr, const unsigned* __restrict__ partialU,
                        int2* __restrict__ ent, int E, int N) {
    __shared__ int cur[NMAX];
    int b = blockIdx.x;
    int halfN = (N + 1) >> 1;
    for (int i = threadIdx.x; i < halfN; i += TPBH) {
        unsigned v = partialU[(size_t)b * halfN + i];
        cur[2 * i] = rowptr[2 * i] + (int)(v & 0xFFFFu);
        if (2 * i + 1 < N) cur[2 * i + 1] = rowptr[2 * i + 1] + (int)(v >> 16);
    }
    __syncthreads();
    int chunk = (E + HB - 1) / HB;
    int e0 = b * chunk;
    int e1 = e0 + chunk; if (e1 > E) e1 = E;
    for (int e = e0 + threadIdx.x; e < e1; e += TPBH) {
        int r, c; load_rc(ei, e, E, r, c);
        int hw = __float_as_int(0.5f * ew[e]);
        int p1 = atomicAdd(&cur[r], 1);
        ent[p1] = make_int2(c, hw);
        int p2 = atomicAdd(&cur[c], 1);
        ent[p2] = make_int2(r, hw);
    }
}

// ---------------- pass E: dis[i] = rsqrt(1 + sum(wgt row i)), wave per node ----------------
__global__ void k_deg_dis(const int* __restrict__ rowptr, const int2* __restrict__ ent,
                          float* __restrict__ dis, int N) {
    int wv = (blockIdx.x * TPB + threadIdx.x) >> 6;
    int lane = threadIdx.x & 63;
    if (wv >= N) return;
    int j0 = rowptr[wv], j1 = rowptr[wv + 1];
    float s = 0.f;
    for (int j = j0 + lane; j < j1; j += 64) s += __int_as_float(ent[j].y);
    #pragma unroll
    for (int off = 32; off; off >>= 1) s += __shfl_down(s, off, 64);
    if (lane == 0) dis[wv] = rsqrtf(1.f + s);
}

// ============ fallback path (N > NMAX): global-atomic prep ============
__global__ void k_init_fb(float* deg, int* counts, int N) {
    int i = blockIdx.x * TPB + threadIdx.x;
    if (i < N) { deg[i] = 1.0f; counts[i] = 0; }
}
__global__ void k_deg_cnt_fb(const int* __restrict__ ei, const float* __restrict__ ew,
                             float* deg, int* counts, int E) {
    int e = blockIdx.x * TPB + threadIdx.x;
    if (e >= E) return;
    int r, c; load_rc(ei, e, E, r, c);
    float hw = 0.5f * ew[e];
    unsafeAtomicAdd(&deg[r], hw);
    unsafeAtomicAdd(&deg[c], hw);
    atomicAdd(&counts[r], 1);
    atomicAdd(&counts[c], 1);
}
__global__ void k_rsqrt_fb(float* degdis, int N) {
    int i = blockIdx.x * TPB + threadIdx.x;
    if (i < N) {
        float d = degdis[i];
        degdis[i] = d > 0.f ? rsqrtf(d) : 0.f;
    }
}
__global__ void k_scan_fb(const int* __restrict__ counts, int* __restrict__ rowptr,
                          int* __restrict__ cursor, int N) {
    __shared__ int partial[TPB];
    int tid = threadIdx.x;
    int chunk = (N + TPB - 1) / TPB;
    int begin = tid * chunk;
    int end = begin + chunk; if (end > N) end = N;
    int s = 0;
    for (int i = begin; i < end; ++i) s += counts[i];
    partial[tid] = s;
    __syncthreads();
    for (int off = 1; off < TPB; off <<= 1) {
        int v = partial[tid];
        int add = (tid >= off) ? partial[tid - off] : 0;
        __syncthreads();
        partial[tid] = v + add;
        __syncthreads();
    }
    int base = (tid == 0) ? 0 : partial[tid - 1];
    for (int i = begin; i < end; ++i) {
        rowptr[i] = base; cursor[i] = base;
        base += counts[i];
    }
    if (tid == TPB - 1) rowptr[N] = base;
}
__global__ void k_fill_fb(const int* __restrict__ ei, const float* __restrict__ ew,
                          int* cursor, int2* __restrict__ ent, int E) {
    int e = blockIdx.x * TPB + threadIdx.x;
    if (e >= E) return;
    int r, c; load_rc(ei, e, E, r, c);
    int hw = __float_as_int(0.5f * ew[e]);
    int p1 = atomicAdd(&cursor[r], 1);
    ent[p1] = make_int2(c, hw);
    int p2 = atomicAdd(&cursor[c], 1);
    ent[p2] = make_int2(r, hw);
}

// ---------------- Z1[N,64] = dis .* (X[N,64] @ W1[64,64]) ----------------
__global__ void k_gemm1(const float* __restrict__ X, const float* __restrict__ W,
                        const float* __restrict__ dis, float* __restrict__ Z, int N) {
    __shared__ float Wl[64 * 64];
    int tid = threadIdx.x;
    #pragma unroll
    for (int i = tid; i < 4096; i += TPB) Wl[i] = W[i];
    __syncthreads();
    int row = blockIdx.x * 4 + (tid >> 6);
    int f = tid & 63;
    if (row >= N) return;
    const float* xr = X + row * 64;
    float s = 0.f;
    #pragma unroll
    for (int k = 0; k < 64; ++k) s = fmaf(xr[k], Wl[k * 64 + f], s);
    Z[row * 64 + f] = dis[row] * s;
}

// ---------------- gather: pipelined cooperative entry load + shuffle bcast + 8-way MLP ----
template <int D, bool RELU>
__global__ void k_gather(const float* __restrict__ Z, const int* __restrict__ rowptr,
                         const int2* __restrict__ ent, const float* __restrict__ dis,
                         const float* __restrict__ bias, float* __restrict__ out,
                         int N, int M) {
    constexpr int NPB = TPB / D;
    int node = blockIdx.x * NPB + threadIdx.x / D;
    int f = threadIdx.x % D;
    int lane = threadIdx.x & 63;
    int base = lane & ~(D - 1);  // group base lane within the wave
    if (node >= N) return;
    int j0 = rowptr[node], j1 = rowptr[node + 1];
    float acc = Z[node * D + f];
    // prime the pipeline: cooperative tile load for the first D entries
    int2 e = make_int2(0, 0);
    if (j0 < j1) {
        int idx = j0 + f; if (idx >= M) idx = M - 1;
        e = ent[idx];
    }
    for (int jb = j0; jb < j1; jb += D) {
        // prefetch next tile before consuming current (hides ent latency)
        int nxt = jb + D;
        int2 en = e;
        if (nxt < j1) {
            int idx = nxt + f; if (idx >= M) idx = M - 1;
            en = ent[idx];
        }
        int cnt = j1 - jb; if (cnt > D) cnt = D;
        int k = 0;
        for (; k + 8 <= cnt; k += 8) {
            int   n[8]; float w[8], z[8];
            #pragma unroll
            for (int u = 0; u < 8; ++u) {
                n[u] = __shfl(e.x, base + k + u);
                w[u] = __int_as_float(__shfl(e.y, base + k + u));
            }
            #pragma unroll
            for (int u = 0; u < 8; ++u) z[u] = Z[n[u] * D + f];  // 8 loads in flight
            #pragma unroll
            for (int u = 0; u < 8; ++u) acc = fmaf(w[u], z[u], acc);
        }
        for (; k < cnt; ++k) {
            int n0 = __shfl(e.x, base + k);
            float w0 = __int_as_float(__shfl(e.y, base + k));
            acc = fmaf(w0, Z[n0 * D + f], acc);
        }
        e = en;
    }
    float v = fmaf(dis[node], acc, bias[f]);
    if (RELU) v = v > 0.f ? v : 0.f;
    out[node * D + f] = v;
}

// ---------------- Z2[N,16] = dis .* (H[N,64] @ W2[64,16]) ----------------
__global__ void k_gemm2(const float* __restrict__ H, const float* __restrict__ W2,
                        const float* __restrict__ dis, float* __restrict__ Z2, int N) {
    __shared__ float Wl[64 * 16];
    int tid = threadIdx.x;
    #pragma unroll
    for (int i = tid; i < 1024; i += TPB) Wl[i] = W2[i];
    __syncthreads();
    int row = blockIdx.x * 16 + (tid >> 4);
    int f = tid & 15;
    if (row >= N) return;
    const float* hr = H + row * 64;
    float s = 0.f;
    #pragma unroll
    for (int k = 0; k < 64; ++k) s = fmaf(hr[k], Wl[k * 16 + f], s);
    Z2[row * 16 + f] = dis[row] * s;
}

extern "C" void kernel_launch(void* const* d_in, const int* in_sizes, int n_in,
                              void* d_out, int out_size, void* d_ws, size_t ws_size,
                              hipStream_t stream) {
    const float* x  = (const float*)d_in[0];
    const float* W1 = (const float*)d_in[1];
    const float* b1 = (const float*)d_in[2];
    const float* W2 = (const float*)d_in[3];
    const float* b2 = (const float*)d_in[4];
    const float* ew = (const float*)d_in[5];
    const int*   ei = (const int*)d_in[6];   // int32 (see evidence note above)

    const int N = in_sizes[0] / 64;   // 16384
    const int E = in_sizes[5];        // 524288
    const int M = 2 * E;              // CSR entries

    char* ws = (char*)d_ws;
    size_t off = 0;
    auto alloc = [&](size_t bytes) -> void* {
        void* p = ws + off;
        off += (bytes + 255) & ~(size_t)255;
        return p;
    };
    float* dis    = (float*)alloc((size_t)N * 4);
    int*   counts = (int*)alloc((size_t)N * 4);
    int*   rowptr = (int*)alloc(((size_t)N + 1) * 4);
    int*   cursor = (int*)alloc((size_t)N * 4);          // fallback path only
    int2*  ent    = (int2*)alloc((size_t)M * 8);         // packed (nbr, wgt_bits)
    float* Z1     = (float*)alloc((size_t)N * 64 * 4);   // partial aliases Z1+H (8 MB)
    float* H      = (float*)alloc((size_t)N * 64 * 4);
    float* Z2     = (float*)alloc((size_t)N * 16 * 4);
    (void)ws_size; (void)n_in; (void)out_size;

    // partialU[HB * ceil(N/2)] uints alias Z1+H (HB=256 -> 8 MB); prep finishes
    // before k_gemm1/k_gather write Z1/H on the same stream.
    unsigned* partialU = (unsigned*)Z1;

    float* out = (float*)d_out;

    if (N <= NMAX) {
        const int halfN = (N + 1) >> 1;
        k_count<<<HB, TPBH, 0, stream>>>(ei, E, partialU, N);
        k_reduce<<<(halfN + TPB - 1) / TPB, TPB, 0, stream>>>(partialU, counts, N);
        k_scan2<<<1, TPB, 0, stream>>>(counts, rowptr, N);
        k_fill2<<<HB, TPBH, 0, stream>>>(ei, ew, rowptr, partialU, ent, E, N);
        k_deg_dis<<<(N * 64 + TPB - 1) / TPB, TPB, 0, stream>>>(rowptr, ent, dis, N);
    } else {
        k_init_fb<<<(N + TPB - 1) / TPB, TPB, 0, stream>>>(dis, counts, N);
        k_deg_cnt_fb<<<(E + TPB - 1) / TPB, TPB, 0, stream>>>(ei, ew, dis, counts, E);
        k_rsqrt_fb<<<(N + TPB - 1) / TPB, TPB, 0, stream>>>(dis, N);
        k_scan_fb<<<1, TPB, 0, stream>>>(counts, rowptr, cursor, N);
        k_fill_fb<<<(E + TPB - 1) / TPB, TPB, 0, stream>>>(ei, ew, cursor, ent, E);
    }

    // layer 1
    k_gemm1<<<(N + 3) / 4, TPB, 0, stream>>>(x, W1, dis, Z1, N);
    k_gather<64, true><<<(N + 3) / 4, TPB, 0, stream>>>(Z1, rowptr, ent, dis, b1, H, N, M);

    // layer 2
    k_gemm2<<<(N + 15) / 16, TPB, 0, stream>>>(H, W2, dis, Z2, N);
    k_gather<16, false><<<(N + 15) / 16, TPB, 0, stream>>>(Z2, rowptr, ent, dis, b2, out, N, M);
}

// Round 7
// 215.792 us; speedup vs baseline: 2.4819x; 1.0167x over previous
//
#include <hip/hip_runtime.h>

constexpr int TPB   = 256;    // generic block
constexpr int NMAX  = 16384;  // fast-path cap (packing: node ids fit 20 bits, rloc 8 bits)
constexpr int GBMAX = 1024;   // fast-path cap on p1 grid (E <= 2M edges)
constexpr int CHUNK = 2048;   // edges per k_p1 block

// edge_index delivered as int32 [2][E] (validated R3 counters + R6 pass).

// ============ fast path: two-level bucket CSR build, coalesced writes ============
// bucket = node >> rsh (RN = 1<<rsh nodes per bucket, NBe = ceil(N/RN) <= 256 buckets)

// ---- p1: partition edge-endpoint entries into per-(block,bucket) runs in tmp ----
__global__ __launch_bounds__(1024) void k_p1(const int* __restrict__ ei,
    const float* __restrict__ ew, int E, int rsh, int NBe,
    int* __restrict__ bstart, int* __restrict__ bcnt, int2* __restrict__ tmp) {
    __shared__ int cnt[256];
    __shared__ int curs[256];
    __shared__ int sc[256];
    __shared__ int2 stg[2 * CHUNK];
    int tid = threadIdx.x;
    int b = blockIdx.x;
    int e0 = b * CHUNK;
    int e1 = min(E, e0 + CHUNK);
    if (tid < NBe) cnt[tid] = 0;
    __syncthreads();
    int ea = e0 + tid, ebg = e0 + 1024 + tid;
    int r0 = 0, c0 = 0, r1 = 0, c1 = 0, w0 = 0, w1 = 0;
    bool va = ea < e1, vb = ebg < e1;
    if (va) { r0 = ei[ea];  c0 = ei[E + ea];  w0 = __float_as_int(0.5f * ew[ea]); }
    if (vb) { r1 = ei[ebg]; c1 = ei[E + ebg]; w1 = __float_as_int(0.5f * ew[ebg]); }
    if (va) { atomicAdd(&cnt[r0 >> rsh], 1); atomicAdd(&cnt[c0 >> rsh], 1); }
    if (vb) { atomicAdd(&cnt[r1 >> rsh], 1); atomicAdd(&cnt[c1 >> rsh], 1); }
    __syncthreads();
    int myc = (tid < NBe) ? cnt[tid] : 0;
    if (tid < NBe) sc[tid] = myc;
    __syncthreads();
    for (int off = 1; off < NBe; off <<= 1) {
        int v = 0;
        if (tid < NBe && tid >= off) v = sc[tid - off];
        __syncthreads();
        if (tid < NBe) sc[tid] += v;
        __syncthreads();
    }
    if (tid < NBe) {
        int excl = sc[tid] - myc;
        curs[tid] = excl;
        bstart[b * NBe + tid] = 2 * e0 + excl;
        bcnt[b * NBe + tid] = myc;
    }
    __syncthreads();
    int mask = (1 << rsh) - 1;
    if (va) {
        int p = atomicAdd(&curs[r0 >> rsh], 1);
        stg[p] = make_int2(((r0 & mask) << 20) | c0, w0);
        p = atomicAdd(&curs[c0 >> rsh], 1);
        stg[p] = make_int2(((c0 & mask) << 20) | r0, w0);
    }
    if (vb) {
        int p = atomicAdd(&curs[r1 >> rsh], 1);
        stg[p] = make_int2(((r1 & mask) << 20) | c1, w1);
        p = atomicAdd(&curs[c1 >> rsh], 1);
        stg[p] = make_int2(((c1 & mask) << 20) | r1, w1);
    }
    __syncthreads();
    int tot = 2 * (e1 - e0);
    for (int i = tid; i < tot; i += 1024) tmp[2 * e0 + i] = stg[i];  // coalesced burst
}

// ---- bscan: per-bucket totals -> exclusive CSR base ----
__global__ void k_bscan(const int* __restrict__ bcnt, int GB, int NBe,
                        int* __restrict__ entBase, int* __restrict__ rowptr,
                        int N, int M) {
    __shared__ int tot[256];
    int k = threadIdx.x;  // 256 threads
    int s = 0;
    if (k < NBe) {
        for (int b = 0; b < GB; ++b) s += bcnt[b * NBe + k];  // coalesced across k
        tot[k] = s;
    }
    __syncthreads();
    for (int off = 1; off < NBe; off <<= 1) {
        int v = 0;
        if (k < NBe && k >= off) v = tot[k - off];
        __syncthreads();
        if (k < NBe) tot[k] += v;
        __syncthreads();
    }
    if (k < NBe) entBase[k] = tot[k] - s;
    if (k == 0) rowptr[N] = M;
}

// ---- p2: per-bucket local sort -> final CSR + rowptr + dis (fused degree) ----
__global__ __launch_bounds__(1024) void k_p2(const int2* __restrict__ tmp,
    const int* __restrict__ bstart, const int* __restrict__ bcnt,
    const int* __restrict__ entBase, int GB, int NBe, int rsh, int N,
    int2* __restrict__ ent, int* __restrict__ rowptr, float* __restrict__ dis) {
    __shared__ int ncnt[256];
    __shared__ int nstart[256];
    __shared__ int ncur[256];
    __shared__ float wsum[256];
    int k = blockIdx.x;
    int tid = threadIdx.x;
    int RN = 1 << rsh;
    int n0 = k << rsh;
    if (tid < RN) { ncnt[tid] = 0; wsum[tid] = 0.f; }
    __syncthreads();
    int eb = entBase[k];
    int grp = tid >> 2, sub = tid & 3;  // 4 threads per source block segment
    // Phase A: node-local histogram
    for (int b = grp; b < GB; b += 256) {
        int s = bstart[b * NBe + k];
        int l = bcnt[b * NBe + k];
        for (int u = sub; u < l; u += 4) {
            int2 v = tmp[s + u];
            atomicAdd(&ncnt[v.x >> 20], 1);
        }
    }
    __syncthreads();
    int myc = (tid < RN) ? ncnt[tid] : 0;
    if (tid < RN) nstart[tid] = myc;
    __syncthreads();
    for (int off = 1; off < RN; off <<= 1) {
        int v = 0;
        if (tid < RN && tid >= off) v = nstart[tid - off];
        __syncthreads();
        if (tid < RN) nstart[tid] += v;
        __syncthreads();
    }
    if (tid < RN) { nstart[tid] -= myc; ncur[tid] = nstart[tid]; }
    __syncthreads();
    // Phase B: scatter into bucket's contiguous CSR region + weight sums
    for (int b = grp; b < GB; b += 256) {
        int s = bstart[b * NBe + k];
        int l = bcnt[b * NBe + k];
        for (int u = sub; u < l; u += 4) {
            int2 v = tmp[s + u];
            int rl = v.x >> 20;
            int cc = v.x & 0xFFFFF;
            int p = atomicAdd(&ncur[rl], 1);
            ent[eb + p] = make_int2(cc, v.y);
            atomicAdd(&wsum[rl], __int_as_float(v.y));  // LDS float atomic
        }
    }
    __syncthreads();
    if (tid < RN && n0 + tid < N) {
        rowptr[n0 + tid] = eb + nstart[tid];
        dis[n0 + tid] = rsqrtf(1.f + wsum[tid]);
    }
}

// ============ fallback path (N > NMAX or E > CHUNK*GBMAX): global-atomic prep ============
__global__ void k_init_fb(float* deg, int* counts, int N) {
    int i = blockIdx.x * TPB + threadIdx.x;
    if (i < N) { deg[i] = 1.0f; counts[i] = 0; }
}
__global__ void k_deg_cnt_fb(const int* __restrict__ ei, const float* __restrict__ ew,
                             float* deg, int* counts, int E) {
    int e = blockIdx.x * TPB + threadIdx.x;
    if (e >= E) return;
    int r = ei[e], c = ei[E + e];
    float hw = 0.5f * ew[e];
    unsafeAtomicAdd(&deg[r], hw);
    unsafeAtomicAdd(&deg[c], hw);
    atomicAdd(&counts[r], 1);
    atomicAdd(&counts[c], 1);
}
__global__ void k_rsqrt_fb(float* degdis, int N) {
    int i = blockIdx.x * TPB + threadIdx.x;
    if (i < N) {
        float d = degdis[i];
        degdis[i] = d > 0.f ? rsqrtf(d) : 0.f;
    }
}
__global__ void k_scan_fb(const int* __restrict__ counts, int* __restrict__ rowptr,
                          int* __restrict__ cursor, int N) {
    __shared__ int partial[TPB];
    int tid = threadIdx.x;
    int chunk = (N + TPB - 1) / TPB;
    int begin = tid * chunk;
    int end = begin + chunk; if (end > N) end = N;
    int s = 0;
    for (int i = begin; i < end; ++i) s += counts[i];
    partial[tid] = s;
    __syncthreads();
    for (int off = 1; off < TPB; off <<= 1) {
        int v = partial[tid];
        int add = (tid >= off) ? partial[tid - off] : 0;
        __syncthreads();
        partial[tid] = v + add;
        __syncthreads();
    }
    int base = (tid == 0) ? 0 : partial[tid - 1];
    for (int i = begin; i < end; ++i) {
        rowptr[i] = base; cursor[i] = base;
        base += counts[i];
    }
    if (tid == TPB - 1) rowptr[N] = base;
}
__global__ void k_fill_fb(const int* __restrict__ ei, const float* __restrict__ ew,
                          int* cursor, int2* __restrict__ ent, int E) {
    int e = blockIdx.x * TPB + threadIdx.x;
    if (e >= E) return;
    int r = ei[e], c = ei[E + e];
    int hw = __float_as_int(0.5f * ew[e]);
    int p1 = atomicAdd(&cursor[r], 1);
    ent[p1] = make_int2(c, hw);
    int p2 = atomicAdd(&cursor[c], 1);
    ent[p2] = make_int2(r, hw);
}

// ---------------- Z1[N,64] = dis .* (X[N,64] @ W1[64,64]) ----------------
__global__ void k_gemm1(const float* __restrict__ X, const float* __restrict__ W,
                        const float* __restrict__ dis, float* __restrict__ Z, int N) {
    __shared__ float Wl[64 * 64];
    int tid = threadIdx.x;
    #pragma unroll
    for (int i = tid; i < 4096; i += TPB) Wl[i] = W[i];
    __syncthreads();
    int row = blockIdx.x * 4 + (tid >> 6);
    int f = tid & 63;
    if (row >= N) return;
    const float* xr = X + row * 64;
    float s = 0.f;
    #pragma unroll
    for (int k = 0; k < 64; ++k) s = fmaf(xr[k], Wl[k * 64 + f], s);
    Z[row * 64 + f] = dis[row] * s;
}

// ---------------- gather: pipelined cooperative entry load + shuffle bcast + 8-way MLP ----
template <int D, bool RELU>
__global__ void k_gather(const float* __restrict__ Z, const int* __restrict__ rowptr,
                         const long long* __restrict__ entq, const float* __restrict__ dis,
                         const float* __restrict__ bias, float* __restrict__ out, int N) {
    constexpr int NPB = TPB / D;
    int node = blockIdx.x * NPB + threadIdx.x / D;
    int f = threadIdx.x % D;
    int lane = threadIdx.x & 63;
    int base = lane & ~(D - 1);
    if (node >= N) return;
    int j0 = rowptr[node], j1 = rowptr[node + 1];
    float acc = Z[node * D + f];
    long long cur = 0;
    if (j0 < j1) cur = __builtin_nontemporal_load(entq + j0 + f);  // ent padded by 64
    for (int jb = j0; jb < j1; jb += D) {
        long long nxt = cur;
        if (jb + D < j1) nxt = __builtin_nontemporal_load(entq + jb + D + f);
        int ex = (int)cur;
        float ey = __int_as_float((int)(cur >> 32));
        int cnt = j1 - jb; if (cnt > D) cnt = D;
        int k = 0;
        for (; k + 8 <= cnt; k += 8) {
            int n[8]; float w[8], z[8];
            #pragma unroll
            for (int u = 0; u < 8; ++u) {
                n[u] = __shfl(ex, base + k + u);
                w[u] = __shfl(ey, base + k + u);
            }
            #pragma unroll
            for (int u = 0; u < 8; ++u) z[u] = Z[n[u] * D + f];
            #pragma unroll
            for (int u = 0; u < 8; ++u) acc = fmaf(w[u], z[u], acc);
        }
        for (; k < cnt; ++k) {
            int n0 = __shfl(ex, base + k);
            float w0 = __shfl(ey, base + k);
            acc = fmaf(w0, Z[n0 * D + f], acc);
        }
        cur = nxt;
    }
    float v = fmaf(dis[node], acc, bias[f]);
    if (RELU) v = v > 0.f ? v : 0.f;
    out[node * D + f] = v;
}

// ---------------- Z2[N,16] = dis .* (H[N,64] @ W2[64,16]) ----------------
__global__ void k_gemm2(const float* __restrict__ H, const float* __restrict__ W2,
                        const float* __restrict__ dis, float* __restrict__ Z2, int N) {
    __shared__ float Wl[64 * 16];
    int tid = threadIdx.x;
    #pragma unroll
    for (int i = tid; i < 1024; i += TPB) Wl[i] = W2[i];
    __syncthreads();
    int row = blockIdx.x * 16 + (tid >> 4);
    int f = tid & 15;
    if (row >= N) return;
    const float* hr = H + row * 64;
    float s = 0.f;
    #pragma unroll
    for (int k = 0; k < 64; ++k) s = fmaf(hr[k], Wl[k * 16 + f], s);
    Z2[row * 16 + f] = dis[row] * s;
}

extern "C" void kernel_launch(void* const* d_in, const int* in_sizes, int n_in,
                              void* d_out, int out_size, void* d_ws, size_t ws_size,
                              hipStream_t stream) {
    const float* x  = (const float*)d_in[0];
    const float* W1 = (const float*)d_in[1];
    const float* b1 = (const float*)d_in[2];
    const float* W2 = (const float*)d_in[3];
    const float* b2 = (const float*)d_in[4];
    const float* ew = (const float*)d_in[5];
    const int*   ei = (const int*)d_in[6];   // int32 layout (validated)

    const int N = in_sizes[0] / 64;   // 16384
    const int E = in_sizes[5];        // 524288
    const int M = 2 * E;              // CSR entries

    // bucket geometry: RN = pow2, NBe = ceil(N/RN) <= 256
    int rsh = 0;
    while ((256 << rsh) < N) ++rsh;
    const int NBe = (N + (1 << rsh) - 1) >> rsh;
    const int GB  = (E + CHUNK - 1) / CHUNK;

    char* ws = (char*)d_ws;
    size_t off = 0;
    auto alloc = [&](size_t bytes) -> void* {
        void* p = ws + off;
        off += (bytes + 255) & ~(size_t)255;
        return p;
    };
    float* dis     = (float*)alloc((size_t)N * 4);
    int*   counts  = (int*)alloc((size_t)N * 4);          // fallback only
    int*   rowptr  = (int*)alloc(((size_t)N + 1) * 4);
    int*   cursor  = (int*)alloc((size_t)N * 4);          // fallback only
    int2*  ent     = (int2*)alloc(((size_t)M + 64) * 8);  // +64 pad: gather reads unclamped
    int*   bstart  = (int*)alloc((size_t)GB * NBe * 4);
    int*   bcnt    = (int*)alloc((size_t)GB * NBe * 4);
    int*   entBase = (int*)alloc(((size_t)NBe + 1) * 4);
    float* Z1      = (float*)alloc((size_t)N * 64 * 4);   // tmp aliases Z1+H (8 MB)
    float* H       = (float*)alloc((size_t)N * 64 * 4);
    float* Z2      = (float*)alloc((size_t)N * 16 * 4);
    (void)ws_size; (void)n_in; (void)out_size;

    // tmp[M] int2 aliases Z1+H (consumed by k_p2 before k_gemm1/k_gather write them)
    int2* tmp = (int2*)Z1;

    float* out = (float*)d_out;

    if (N <= NMAX && GB <= GBMAX) {
        k_p1<<<GB, 1024, 0, stream>>>(ei, ew, E, rsh, NBe, bstart, bcnt, tmp);
        k_bscan<<<1, 256, 0, stream>>>(bcnt, GB, NBe, entBase, rowptr, N, M);
        k_p2<<<NBe, 1024, 0, stream>>>(tmp, bstart, bcnt, entBase, GB, NBe, rsh, N,
                                       ent, rowptr, dis);
    } else {
        k_init_fb<<<(N + TPB - 1) / TPB, TPB, 0, stream>>>(dis, counts, N);
        k_deg_cnt_fb<<<(E + TPB - 1) / TPB, TPB, 0, stream>>>(ei, ew, dis, counts, E);
        k_rsqrt_fb<<<(N + TPB - 1) / TPB, TPB, 0, stream>>>(dis, N);
        k_scan_fb<<<1, TPB, 0, stream>>>(counts, rowptr, cursor, N);
        k_fill_fb<<<(E + TPB - 1) / TPB, TPB, 0, stream>>>(ei, ew, cursor, ent, E);
    }

    // layer 1
    k_gemm1<<<(N + 3) / 4, TPB, 0, stream>>>(x, W1, dis, Z1, N);
    k_gather<64, true><<<(N + 3) / 4, TPB, 0, stream>>>(Z1, rowptr, (const long long*)ent,
                                                        dis, b1, H, N);
    // layer 2
    k_gemm2<<<(N + 15) / 16, TPB, 0, stream>>>(H, W2, dis, Z2, N);
    k_gather<16, false><<<(N + 15) / 16, TPB, 0, stream>>>(Z2, rowptr, (const long long*)ent,
                                                           dis, b2, out, N);
}

// Round 8
// 156.777 us; speedup vs baseline: 3.4161x; 1.3764x over previous
//
#include <hip/hip_runtime.h>

constexpr int TPB   = 256;    // generic block
constexpr int NMAX  = 16384;  // fast-path cap (packing: node ids fit 20 bits, rloc 8 bits)
constexpr int GBMAX = 1024;   // fast-path cap on p1 grid (E <= 2M edges)
constexpr int CHUNK = 2048;   // edges per k_p1 block

// edge_index delivered as int32 [2][E] (validated R3 counters + R6 pass).

// ============ fast path: two-level bucket CSR build, coalesced writes ============
// bucket = node >> rsh (RN = 1<<rsh nodes per bucket, NBe = ceil(N/RN) <= 256 buckets)
// Per-(block,bucket) tables stored TRANSPOSED [k*GB + b] so column ops are contiguous.

// ---- p1: partition edge-endpoint entries into per-(block,bucket) runs in tmp ----
__global__ __launch_bounds__(1024) void k_p1(const int* __restrict__ ei,
    const float* __restrict__ ew, int E, int rsh, int NBe, int GB,
    int* __restrict__ bstartT, int* __restrict__ bcntT, int2* __restrict__ tmp) {
    __shared__ int cnt[256];
    __shared__ int curs[256];
    __shared__ int sc[256];
    __shared__ int2 stg[2 * CHUNK];
    int tid = threadIdx.x;
    int b = blockIdx.x;
    int e0 = b * CHUNK;
    int e1 = min(E, e0 + CHUNK);
    if (tid < NBe) cnt[tid] = 0;
    __syncthreads();
    int ea = e0 + tid, ebg = e0 + 1024 + tid;
    int r0 = 0, c0 = 0, r1 = 0, c1 = 0, w0 = 0, w1 = 0;
    bool va = ea < e1, vb = ebg < e1;
    if (va) { r0 = ei[ea];  c0 = ei[E + ea];  w0 = __float_as_int(0.5f * ew[ea]); }
    if (vb) { r1 = ei[ebg]; c1 = ei[E + ebg]; w1 = __float_as_int(0.5f * ew[ebg]); }
    if (va) { atomicAdd(&cnt[r0 >> rsh], 1); atomicAdd(&cnt[c0 >> rsh], 1); }
    if (vb) { atomicAdd(&cnt[r1 >> rsh], 1); atomicAdd(&cnt[c1 >> rsh], 1); }
    __syncthreads();
    int myc = (tid < NBe) ? cnt[tid] : 0;
    if (tid < NBe) sc[tid] = myc;
    __syncthreads();
    for (int off = 1; off < NBe; off <<= 1) {
        int v = 0;
        if (tid < NBe && tid >= off) v = sc[tid - off];
        __syncthreads();
        if (tid < NBe) sc[tid] += v;
        __syncthreads();
    }
    if (tid < NBe) {
        int excl = sc[tid] - myc;
        curs[tid] = excl;
        bstartT[tid * GB + b] = 2 * e0 + excl;   // transposed
        bcntT[tid * GB + b] = myc;
    }
    __syncthreads();
    int mask = (1 << rsh) - 1;
    if (va) {
        int p = atomicAdd(&curs[r0 >> rsh], 1);
        stg[p] = make_int2(((r0 & mask) << 20) | c0, w0);
        p = atomicAdd(&curs[c0 >> rsh], 1);
        stg[p] = make_int2(((c0 & mask) << 20) | r0, w0);
    }
    if (vb) {
        int p = atomicAdd(&curs[r1 >> rsh], 1);
        stg[p] = make_int2(((r1 & mask) << 20) | c1, w1);
        p = atomicAdd(&curs[c1 >> rsh], 1);
        stg[p] = make_int2(((c1 & mask) << 20) | r1, w1);
    }
    __syncthreads();
    int tot = 2 * (e1 - e0);
    for (int i = tid; i < tot; i += 1024) tmp[2 * e0 + i] = stg[i];  // coalesced burst
}

// ---- colsum: one block per bucket, contiguous coalesced row sum -> btot[k] ----
__global__ void k_colsum(const int* __restrict__ bcntT, int GB,
                         int* __restrict__ btot) {
    __shared__ int red[TPB / 64];
    int k = blockIdx.x;
    int s = 0;
    for (int b = threadIdx.x; b < GB; b += TPB) s += bcntT[k * GB + b];
    #pragma unroll
    for (int off = 32; off; off >>= 1) s += __shfl_down(s, off, 64);
    int wv = threadIdx.x >> 6;
    if ((threadIdx.x & 63) == 0) red[wv] = s;
    __syncthreads();
    if (threadIdx.x == 0) {
        int t = 0;
        for (int w = 0; w < TPB / 64; ++w) t += red[w];
        btot[k] = t;
    }
}

// ---- scan256: tiny single-block exclusive scan of btot -> entBase ----
__global__ void k_scan256(const int* __restrict__ btot, int NBe,
                          int* __restrict__ entBase, int* __restrict__ rowptr,
                          int N, int M) {
    __shared__ int tot[256];
    int k = threadIdx.x;
    int s = (k < NBe) ? btot[k] : 0;
    tot[k] = s;
    __syncthreads();
    for (int off = 1; off < 256; off <<= 1) {
        int v = (k >= off) ? tot[k - off] : 0;
        __syncthreads();
        tot[k] += v;
        __syncthreads();
    }
    if (k < NBe) entBase[k] = tot[k] - s;
    if (k == 0) rowptr[N] = M;
}

// ---- p2: per-bucket local sort -> final CSR + rowptr + dis (fused degree) ----
__global__ __launch_bounds__(1024) void k_p2(const int2* __restrict__ tmp,
    const int* __restrict__ bstartT, const int* __restrict__ bcntT,
    const int* __restrict__ entBase, int GB, int rsh, int N,
    int2* __restrict__ ent, int* __restrict__ rowptr, float* __restrict__ dis) {
    __shared__ int ncnt[256];
    __shared__ int nstart[256];
    __shared__ int ncur[256];
    __shared__ float wsum[256];
    int k = blockIdx.x;
    int tid = threadIdx.x;
    int RN = 1 << rsh;
    int n0 = k << rsh;
    if (tid < RN) { ncnt[tid] = 0; wsum[tid] = 0.f; }
    __syncthreads();
    int eb = entBase[k];
    int grp = tid >> 2, sub = tid & 3;  // 4 threads per source block segment
    // Phase A: node-local histogram
    for (int b = grp; b < GB; b += 256) {
        int s = bstartT[k * GB + b];
        int l = bcntT[k * GB + b];
        for (int u = sub; u < l; u += 4) {
            int2 v = tmp[s + u];
            atomicAdd(&ncnt[v.x >> 20], 1);
        }
    }
    __syncthreads();
    int myc = (tid < RN) ? ncnt[tid] : 0;
    if (tid < RN) nstart[tid] = myc;
    __syncthreads();
    for (int off = 1; off < RN; off <<= 1) {
        int v = 0;
        if (tid < RN && tid >= off) v = nstart[tid - off];
        __syncthreads();
        if (tid < RN) nstart[tid] += v;
        __syncthreads();
    }
    if (tid < RN) { nstart[tid] -= myc; ncur[tid] = nstart[tid]; }
    __syncthreads();
    // Phase B: scatter into bucket's contiguous CSR region + weight sums
    for (int b = grp; b < GB; b += 256) {
        int s = bstartT[k * GB + b];
        int l = bcntT[k * GB + b];
        for (int u = sub; u < l; u += 4) {
            int2 v = tmp[s + u];
            int rl = v.x >> 20;
            int cc = v.x & 0xFFFFF;
            int p = atomicAdd(&ncur[rl], 1);
            ent[eb + p] = make_int2(cc, v.y);
            atomicAdd(&wsum[rl], __int_as_float(v.y));  // LDS float atomic
        }
    }
    __syncthreads();
    if (tid < RN && n0 + tid < N) {
        rowptr[n0 + tid] = eb + nstart[tid];
        dis[n0 + tid] = rsqrtf(1.f + wsum[tid]);
    }
}

// ============ fallback path (N > NMAX or E > CHUNK*GBMAX): global-atomic prep ============
__global__ void k_init_fb(float* deg, int* counts, int N) {
    int i = blockIdx.x * TPB + threadIdx.x;
    if (i < N) { deg[i] = 1.0f; counts[i] = 0; }
}
__global__ void k_deg_cnt_fb(const int* __restrict__ ei, const float* __restrict__ ew,
                             float* deg, int* counts, int E) {
    int e = blockIdx.x * TPB + threadIdx.x;
    if (e >= E) return;
    int r = ei[e], c = ei[E + e];
    float hw = 0.5f * ew[e];
    unsafeAtomicAdd(&deg[r], hw);
    unsafeAtomicAdd(&deg[c], hw);
    atomicAdd(&counts[r], 1);
    atomicAdd(&counts[c], 1);
}
__global__ void k_rsqrt_fb(float* degdis, int N) {
    int i = blockIdx.x * TPB + threadIdx.x;
    if (i < N) {
        float d = degdis[i];
        degdis[i] = d > 0.f ? rsqrtf(d) : 0.f;
    }
}
__global__ void k_scan_fb(const int* __restrict__ counts, int* __restrict__ rowptr,
                          int* __restrict__ cursor, int N) {
    __shared__ int partial[TPB];
    int tid = threadIdx.x;
    int chunk = (N + TPB - 1) / TPB;
    int begin = tid * chunk;
    int end = begin + chunk; if (end > N) end = N;
    int s = 0;
    for (int i = begin; i < end; ++i) s += counts[i];
    partial[tid] = s;
    __syncthreads();
    for (int off = 1; off < TPB; off <<= 1) {
        int v = partial[tid];
        int add = (tid >= off) ? partial[tid - off] : 0;
        __syncthreads();
        partial[tid] = v + add;
        __syncthreads();
    }
    int base = (tid == 0) ? 0 : partial[tid - 1];
    for (int i = begin; i < end; ++i) {
        rowptr[i] = base; cursor[i] = base;
        base += counts[i];
    }
    if (tid == TPB - 1) rowptr[N] = base;
}
__global__ void k_fill_fb(const int* __restrict__ ei, const float* __restrict__ ew,
                          int* cursor, int2* __restrict__ ent, int E) {
    int e = blockIdx.x * TPB + threadIdx.x;
    if (e >= E) return;
    int r = ei[e], c = ei[E + e];
    int hw = __float_as_int(0.5f * ew[e]);
    int p1 = atomicAdd(&cursor[r], 1);
    ent[p1] = make_int2(c, hw);
    int p2 = atomicAdd(&cursor[c], 1);
    ent[p2] = make_int2(r, hw);
}

// ---------------- Z1[N,64] = dis .* (X[N,64] @ W1[64,64]) ----------------
__global__ void k_gemm1(const float* __restrict__ X, const float* __restrict__ W,
                        const float* __restrict__ dis, float* __restrict__ Z, int N) {
    __shared__ float Wl[64 * 64];
    int tid = threadIdx.x;
    #pragma unroll
    for (int i = tid; i < 4096; i += TPB) Wl[i] = W[i];
    __syncthreads();
    int row = blockIdx.x * 4 + (tid >> 6);
    int f = tid & 63;
    if (row >= N) return;
    const float* xr = X + row * 64;
    float s = 0.f;
    #pragma unroll
    for (int k = 0; k < 64; ++k) s = fmaf(xr[k], Wl[k * 64 + f], s);
    Z[row * 64 + f] = dis[row] * s;
}

// ---------------- gather: pipelined cooperative entry load + shuffle bcast + 8-way MLP ----
template <int D, bool RELU>
__global__ void k_gather(const float* __restrict__ Z, const int* __restrict__ rowptr,
                         const long long* __restrict__ entq, const float* __restrict__ dis,
                         const float* __restrict__ bias, float* __restrict__ out, int N) {
    constexpr int NPB = TPB / D;
    int node = blockIdx.x * NPB + threadIdx.x / D;
    int f = threadIdx.x % D;
    int lane = threadIdx.x & 63;
    int base = lane & ~(D - 1);
    if (node >= N) return;
    int j0 = rowptr[node], j1 = rowptr[node + 1];
    float acc = Z[node * D + f];
    long long cur = 0;
    if (j0 < j1) cur = __builtin_nontemporal_load(entq + j0 + f);  // ent padded by 64
    for (int jb = j0; jb < j1; jb += D) {
        long long nxt = cur;
        if (jb + D < j1) nxt = __builtin_nontemporal_load(entq + jb + D + f);
        int ex = (int)cur;
        float ey = __int_as_float((int)(cur >> 32));
        int cnt = j1 - jb; if (cnt > D) cnt = D;
        int k = 0;
        for (; k + 8 <= cnt; k += 8) {
            int n[8]; float w[8], z[8];
            #pragma unroll
            for (int u = 0; u < 8; ++u) {
                n[u] = __shfl(ex, base + k + u);
                w[u] = __shfl(ey, base + k + u);
            }
            #pragma unroll
            for (int u = 0; u < 8; ++u) z[u] = Z[n[u] * D + f];
            #pragma unroll
            for (int u = 0; u < 8; ++u) acc = fmaf(w[u], z[u], acc);
        }
        for (; k < cnt; ++k) {
            int n0 = __shfl(ex, base + k);
            float w0 = __shfl(ey, base + k);
            acc = fmaf(w0, Z[n0 * D + f], acc);
        }
        cur = nxt;
    }
    float v = fmaf(dis[node], acc, bias[f]);
    if (RELU) v = v > 0.f ? v : 0.f;
    out[node * D + f] = v;
}

// ---------------- Z2[N,16] = dis .* (H[N,64] @ W2[64,16]) ----------------
__global__ void k_gemm2(const float* __restrict__ H, const float* __restrict__ W2,
                        const float* __restrict__ dis, float* __restrict__ Z2, int N) {
    __shared__ float Wl[64 * 16];
    int tid = threadIdx.x;
    #pragma unroll
    for (int i = tid; i < 1024; i += TPB) Wl[i] = W2[i];
    __syncthreads();
    int row = blockIdx.x * 16 + (tid >> 4);
    int f = tid & 15;
    if (row >= N) return;
    const float* hr = H + row * 64;
    float s = 0.f;
    #pragma unroll
    for (int k = 0; k < 64; ++k) s = fmaf(hr[k], Wl[k * 16 + f], s);
    Z2[row * 16 + f] = dis[row] * s;
}

extern "C" void kernel_launch(void* const* d_in, const int* in_sizes, int n_in,
                              void* d_out, int out_size, void* d_ws, size_t ws_size,
                              hipStream_t stream) {
    const float* x  = (const float*)d_in[0];
    const float* W1 = (const float*)d_in[1];
    const float* b1 = (const float*)d_in[2];
    const float* W2 = (const float*)d_in[3];
    const float* b2 = (const float*)d_in[4];
    const float* ew = (const float*)d_in[5];
    const int*   ei = (const int*)d_in[6];   // int32 layout (validated)

    const int N = in_sizes[0] / 64;   // 16384
    const int E = in_sizes[5];        // 524288
    const int M = 2 * E;              // CSR entries

    // bucket geometry: RN = pow2, NBe = ceil(N/RN) <= 256
    int rsh = 0;
    while ((256 << rsh) < N) ++rsh;
    const int NBe = (N + (1 << rsh) - 1) >> rsh;
    const int GB  = (E + CHUNK - 1) / CHUNK;

    char* ws = (char*)d_ws;
    size_t off = 0;
    auto alloc = [&](size_t bytes) -> void* {
        void* p = ws + off;
        off += (bytes + 255) & ~(size_t)255;
        return p;
    };
    float* dis     = (float*)alloc((size_t)N * 4);
    int*   counts  = (int*)alloc((size_t)N * 4);          // fallback only
    int*   rowptr  = (int*)alloc(((size_t)N + 1) * 4);
    int*   cursor  = (int*)alloc((size_t)N * 4);          // fallback only
    int2*  ent     = (int2*)alloc(((size_t)M + 64) * 8);  // +64 pad: gather reads unclamped
    int*   bstartT = (int*)alloc((size_t)GB * NBe * 4);   // [k*GB + b]
    int*   bcntT   = (int*)alloc((size_t)GB * NBe * 4);   // [k*GB + b]
    int*   btot    = (int*)alloc(((size_t)NBe + 1) * 4);
    int*   entBase = (int*)alloc(((size_t)NBe + 1) * 4);
    float* Z1      = (float*)alloc((size_t)N * 64 * 4);   // tmp aliases Z1+H (8 MB)
    float* H       = (float*)alloc((size_t)N * 64 * 4);
    float* Z2      = (float*)alloc((size_t)N * 16 * 4);
    (void)ws_size; (void)n_in; (void)out_size;

    // tmp[M] int2 aliases Z1+H (consumed by k_p2 before k_gemm1/k_gather write them)
    int2* tmp = (int2*)Z1;

    float* out = (float*)d_out;

    if (N <= NMAX && GB <= GBMAX) {
        k_p1<<<GB, 1024, 0, stream>>>(ei, ew, E, rsh, NBe, GB, bstartT, bcntT, tmp);
        k_colsum<<<NBe, TPB, 0, stream>>>(bcntT, GB, btot);
        k_scan256<<<1, 256, 0, stream>>>(btot, NBe, entBase, rowptr, N, M);
        k_p2<<<NBe, 1024, 0, stream>>>(tmp, bstartT, bcntT, entBase, GB, rsh, N,
                                       ent, rowptr, dis);
    } else {
        k_init_fb<<<(N + TPB - 1) / TPB, TPB, 0, stream>>>(dis, counts, N);
        k_deg_cnt_fb<<<(E + TPB - 1) / TPB, TPB, 0, stream>>>(ei, ew, dis, counts, E);
        k_rsqrt_fb<<<(N + TPB - 1) / TPB, TPB, 0, stream>>>(dis, N);
        k_scan_fb<<<1, TPB, 0, stream>>>(counts, rowptr, cursor, N);
        k_fill_fb<<<(E + TPB - 1) / TPB, TPB, 0, stream>>>(ei, ew, cursor, ent, E);
    }

    // layer 1
    k_gemm1<<<(N + 3) / 4, TPB, 0, stream>>>(x, W1, dis, Z1, N);
    k_gather<64, true><<<(N + 3) / 4, TPB, 0, stream>>>(Z1, rowptr, (const long long*)ent,
                                                        dis, b1, H, N);
    // layer 2
    k_gemm2<<<(N + 15) / 16, TPB, 0, stream>>>(H, W2, dis, Z2, N);
    k_gather<16, false><<<(N + 15) / 16, TPB, 0, stream>>>(Z2, rowptr, (const long long*)ent,
                                                           dis, b2, out, N);
}